// Round 1
// baseline (5604.921 us; speedup 1.0000x reference)
//
#include <hip/hip_runtime.h>

typedef unsigned int u32;
typedef unsigned short u16;

#define NN 100000
#define EE 1600000
#define SS 10000
#define GG 256
#define NSCAN ((NN + 1023) / 1024)

// param block offsets (f32 elements)
#define O_W1   0
#define O_B1   65536
#define O_G1   66048
#define O_BE1  66560
#define O_W2   67072
#define O_B2   132608
#define O_G2   133120
#define O_BE2  133632
#define O_EPS  134144
#define O_L1W  134148
#define O_L1B  199684
#define O_L2W  199812
#define O_L2B  201092
#define NPAR   201102

typedef __bf16 bf16x8_t __attribute__((ext_vector_type(8)));
typedef float f32x4_t __attribute__((ext_vector_type(4)));
typedef u32 u32x4_t __attribute__((ext_vector_type(4)));

__device__ __forceinline__ float bf2f(u16 u) {
  union { u32 i; float f; } x; x.i = ((u32)u) << 16; return x.f;
}
__device__ __forceinline__ u16 f2bf(float f) {
  union { float f; u32 i; } x; x.f = f;
  u32 r = x.i + 0x7fffu + ((x.i >> 16) & 1u);
  return (u16)(r >> 16);
}
__device__ __forceinline__ int lbound(const int* __restrict__ a, int n, int key) {
  int lo = 0, hi = n;
  while (lo < hi) { int mid = (lo + hi) >> 1; if (a[mid] < key) lo = mid + 1; else hi = mid; }
  return lo;
}

// ---------------- dtype sniff: 1 = inputs are f32, 0 = bf16 ----------------
__global__ void k_sniff(const u16* __restrict__ x, int* __restrict__ flag) {
  __shared__ int cnt;
  if (threadIdx.x == 0) cnt = 0;
  __syncthreads();
  int weird = 0;
  for (int i = threadIdx.x; i < 8192; i += 256) {
    u16 v = x[i];
    int e = (v >> 7) & 0xff;
    if (e >= 0xC0) weird++;
  }
  atomicAdd(&cnt, weird);
  __syncthreads();
  if (threadIdx.x == 0) *flag = (cnt > 64) ? 1 : 0;
}

// ---------------- convert all params into f32 block P ----------------
__global__ __launch_bounds__(256) void k_cvt_params(
    const void* pW1, const void* pb1, const void* pg1, const void* pbe1,
    const void* pW2, const void* pb2, const void* pg2, const void* pbe2,
    const void* peps, const void* pl1w, const void* pl1b, const void* pl2w, const void* pl2b,
    const int* __restrict__ flagp, float* __restrict__ P) {
  int i = blockIdx.x * 256 + threadIdx.x;
  if (i >= NPAR) return;
  const void* src; int rel;
  if      (i < O_B1)  { src = pW1;  rel = i - O_W1; }
  else if (i < O_G1)  { src = pb1;  rel = i - O_B1; }
  else if (i < O_BE1) { src = pg1;  rel = i - O_G1; }
  else if (i < O_W2)  { src = pbe1; rel = i - O_BE1; }
  else if (i < O_B2)  { src = pW2;  rel = i - O_W2; }
  else if (i < O_G2)  { src = pb2;  rel = i - O_B2; }
  else if (i < O_BE2) { src = pg2;  rel = i - O_G2; }
  else if (i < O_EPS) { src = pbe2; rel = i - O_BE2; }
  else if (i < O_L1W) { src = peps; rel = i - O_EPS; }
  else if (i < O_L1B) { src = pl1w; rel = i - O_L1W; }
  else if (i < O_L2W) { src = pl1b; rel = i - O_L1B; }
  else if (i < O_L2B) { src = pl2w; rel = i - O_L2W; }
  else                { src = pl2b; rel = i - O_L2B; }
  float v = (*flagp) ? ((const float*)src)[rel] : bf2f(((const u16*)src)[rel]);
  P[i] = v;
}

// ---------------- W1/W2 -> bf16 ----------------
__global__ __launch_bounds__(256) void k_cvtW(const float* __restrict__ P,
                                              u16* __restrict__ W1b, u16* __restrict__ W2b) {
  int i = blockIdx.x * 256 + threadIdx.x;
  if (i >= 131072) return;
  if (i < 65536) W1b[i] = f2bf(P[O_W1 + i]);
  else           W2b[i - 65536] = f2bf(P[O_W2 + i - 65536]);
}

// ---------------- x -> Z0 bf16 ----------------
__global__ __launch_bounds__(256) void k_prep(const void* __restrict__ x, const int* __restrict__ flagp,
                                              u16* __restrict__ Z0) {
  int i = blockIdx.x * 256 + threadIdx.x;
  if (i >= (NN * 128) / 8) return;
  if (*flagp) {
    const float4* xf = (const float4*)x;
    float4 a = xf[i * 2], b = xf[i * 2 + 1];
    u32x4_t o;
    o[0] = (u32)f2bf(a.x) | ((u32)f2bf(a.y) << 16);
    o[1] = (u32)f2bf(a.z) | ((u32)f2bf(a.w) << 16);
    o[2] = (u32)f2bf(b.x) | ((u32)f2bf(b.y) << 16);
    o[3] = (u32)f2bf(b.z) | ((u32)f2bf(b.w) << 16);
    *(u32x4_t*)(Z0 + i * 8) = o;
  } else {
    *(u32x4_t*)(Z0 + i * 8) = ((const u32x4_t*)x)[i];
  }
}

// ---------------- CSR build ----------------
__global__ __launch_bounds__(256) void k_hist(const int* __restrict__ dst, int* __restrict__ cnt) {
  int i = blockIdx.x * 256 + threadIdx.x;
  if (i < EE) atomicAdd(&cnt[dst[i]], 1);
}

__global__ __launch_bounds__(256) void k_scan1(const int* __restrict__ cnt, int* __restrict__ bsum) {
  __shared__ int sh[256];
  int base = blockIdx.x * 1024 + threadIdx.x * 4;
  int s = 0;
#pragma unroll
  for (int i = 0; i < 4; i++) { int idx = base + i; s += (idx < NN) ? cnt[idx] : 0; }
  sh[threadIdx.x] = s; __syncthreads();
  for (int o = 128; o > 0; o >>= 1) {
    if (threadIdx.x < o) sh[threadIdx.x] += sh[threadIdx.x + o];
    __syncthreads();
  }
  if (threadIdx.x == 0) bsum[blockIdx.x] = sh[0];
}

__global__ void k_scan2(int* __restrict__ bsum, int* __restrict__ off) {
  if (threadIdx.x == 0 && blockIdx.x == 0) {
    int run = 0;
    for (int i = 0; i < NSCAN; i++) { int v = bsum[i]; bsum[i] = run; run += v; }
    off[NN] = run;
  }
}

__global__ __launch_bounds__(256) void k_scan3(const int* __restrict__ cnt, const int* __restrict__ bsum,
                                               int* __restrict__ off) {
  __shared__ int sh[256];
  int base = blockIdx.x * 1024 + threadIdx.x * 4;
  int v[4]; int s = 0;
#pragma unroll
  for (int i = 0; i < 4; i++) { int idx = base + i; v[i] = (idx < NN) ? cnt[idx] : 0; s += v[i]; }
  sh[threadIdx.x] = s; __syncthreads();
  for (int o = 1; o < 256; o <<= 1) {
    int add = (threadIdx.x >= o) ? sh[threadIdx.x - o] : 0;
    __syncthreads();
    sh[threadIdx.x] += add;
    __syncthreads();
  }
  int run = sh[threadIdx.x] - s + bsum[blockIdx.x];
#pragma unroll
  for (int i = 0; i < 4; i++) { int idx = base + i; if (idx < NN) { off[idx] = run; run += v[i]; } }
}

__global__ __launch_bounds__(256) void k_fill(const int* __restrict__ src, const int* __restrict__ dst,
                                              const int* __restrict__ off, int* __restrict__ cur,
                                              int* __restrict__ csr) {
  int i = blockIdx.x * 256 + threadIdx.x;
  if (i >= EE) return;
  int d = dst[i];
  int p = off[d] + atomicAdd(&cur[d], 1);
  csr[p] = src[i];
}

// ---------------- fused: gather-agg (LDS f32 atomic acc) -> GEMM(W1) + stats1 ----------------
// v2: edges decoupled from rows via ds_add_f32 accumulation; reg-staged indices,
// readlane -> SGPR-base gathers, 16-deep load pipelining, no per-batch vmcnt(0) drain.
#define ACC_STRIDE 132   // dwords: Lo cols at [0..63], Hi cols at [68..131]; 528B row (16B aligned)
#define ACC_HI 68
#define ECAP 384         // staged edge capacity per wave (mean 256, +8 sigma)
__global__ __launch_bounds__(256, 4) void k_agg_gemm(
    const u16* __restrict__ Z, const int* __restrict__ off, const int* __restrict__ csr,
    const u16* __restrict__ Wb, const float* __restrict__ bias, const float* __restrict__ P,
    int layer, u16* __restrict__ H, float* __restrict__ st) {
  __shared__ __align__(16) float acc[4][17 * ACC_STRIDE];  // 17th row = dummy sink
  __shared__ float sst[4][256];
  int wave = threadIdx.x >> 6, lane = threadIdx.x & 63;
  int r0 = blockIdx.x * 64 + wave * 16;
  float ev = 1.0f + P[O_EPS + layer];
  const u32* zr = (const u32*)Z;
  float* aw = &acc[wave][0];

  // prefetch off[r0 .. r0+16] (clamped) via lanes 0..16
  int offv = 0;
  if (lane <= 16) {
    int rr = r0 + lane; if (rr > NN) rr = NN; if (rr < 0) rr = 0;
    offv = off[rr];
  }
  int ebase = __shfl(offv, 0, 64);
  int eend  = __shfl(offv, 16, 64);
  int ntot = eend - ebase;

  // init accumulators with self term (1+eps)*x ; zero dummy row
  for (int rr = 0; rr < 16; rr++) {
    int row = r0 + rr;
    u32 d = (row < NN) ? zr[row * 64 + lane] : 0u;
    float flo = ev * __builtin_bit_cast(float, d << 16);
    float fhi = ev * __builtin_bit_cast(float, d & 0xffff0000u);
    aw[rr * ACC_STRIDE + lane] = flo;
    aw[rr * ACC_STRIDE + ACC_HI + lane] = fhi;
  }
  aw[16 * ACC_STRIDE + lane] = 0.f;
  aw[16 * ACC_STRIDE + ACC_HI + lane] = 0.f;

  // stage up to ECAP edge (row,idx) pairs in registers; row via 4-step shfl binary search
  u32 pk[6];
#pragma unroll
  for (int k = 0; k < 6; k++) {
    pk[k] = 16u << 20;  // dummy: row 16, idx 0
    if (k * 64 < ntot) {
      int f = k * 64 + lane;
      int ci = ebase + f; if (ci >= EE) ci = EE - 1;
      int idx = csr[ci];
      int pos = ebase + f;
      int r = 0, t, v;
      t = r + 8; v = __shfl(offv, t, 64); if (pos >= v) r = t;
      t = r + 4; v = __shfl(offv, t, 64); if (pos >= v) r = t;
      t = r + 2; v = __shfl(offv, t, 64); if (pos >= v) r = t;
      t = r + 1; v = __shfl(offv, t, 64); if (pos >= v) r = t;
      if (f < ntot) pk[k] = (u32)idx | ((u32)r << 20);
    }
  }

  // edge mega-loop: windows of 16 independent gathers, accumulate via LDS f32 atomics
#pragma unroll
  for (int k = 0; k < 6; k++) {
    if (k * 64 < ntot) {
      u32 pkr = pk[k];
#pragma unroll
      for (int w2 = 0; w2 < 4; w2++) {
        if (k * 64 + w2 * 16 < ntot) {
          u32 d[16];
          int ro[16];
#pragma unroll
          for (int i = 0; i < 16; i++) {
            u32 s = (u32)__builtin_amdgcn_readlane((int)pkr, w2 * 16 + i);
            u32 idx = s & 0xFFFFFu;
            ro[i] = (int)(s >> 20);
            d[i] = zr[idx * 64u + lane];
          }
#pragma unroll
          for (int i = 0; i < 16; i++) {
            float flo = __builtin_bit_cast(float, d[i] << 16);
            float fhi = __builtin_bit_cast(float, d[i] & 0xffff0000u);
            float* rb = aw + ro[i] * ACC_STRIDE;
            (void)__hip_atomic_fetch_add(rb + lane, flo, __ATOMIC_RELAXED, __HIP_MEMORY_SCOPE_WORKGROUP);
            (void)__hip_atomic_fetch_add(rb + ACC_HI + lane, fhi, __ATOMIC_RELAXED, __HIP_MEMORY_SCOPE_WORKGROUP);
          }
        }
      }
    }
  }

  // rare overflow fallback (ntot > ECAP): exact, uniform-branch, per-row remainder
  if (ntot > ECAP) {
    for (int rr = 0; rr < 16; rr++) {
      int s = __shfl(offv, rr, 64), e = __shfl(offv, rr + 1, 64);
      int st_ = (s >= ebase + ECAP) ? s : (ebase + ECAP);
      for (int p = st_; p < e; p++) {
        u32 dd2 = zr[(u32)csr[p] * 64u + lane];
        float* rb = aw + rr * ACC_STRIDE;
        (void)__hip_atomic_fetch_add(rb + lane, __builtin_bit_cast(float, dd2 << 16),
                                     __ATOMIC_RELAXED, __HIP_MEMORY_SCOPE_WORKGROUP);
        (void)__hip_atomic_fetch_add(rb + ACC_HI + lane, __builtin_bit_cast(float, dd2 & 0xffff0000u),
                                     __ATOMIC_RELAXED, __HIP_MEMORY_SCOPE_WORKGROUP);
      }
    }
  }

  // MFMA over the wave-private accumulator tile (wave-private -> no barrier needed)
  int nidx = lane & 15, q = lane >> 4;
  f32x4_t accv[8];
  f32x4_t z4 = {0.f, 0.f, 0.f, 0.f};
#pragma unroll
  for (int ot = 0; ot < 8; ot++) accv[ot] = z4;
#pragma unroll
  for (int ks = 0; ks < 4; ks++) {
    f32x4_t lo4 = *(const f32x4_t*)(aw + nidx * ACC_STRIDE + ks * 16 + q * 4);
    f32x4_t hi4 = *(const f32x4_t*)(aw + nidx * ACC_STRIDE + ACC_HI + ks * 16 + q * 4);
    u32x4_t w;
#pragma unroll
    for (int i = 0; i < 4; i++)
      w[i] = (u32)f2bf(lo4[i]) | ((u32)f2bf(hi4[i]) << 16);
    bf16x8_t af = __builtin_bit_cast(bf16x8_t, w);
#pragma unroll
    for (int ot = 0; ot < 8; ot++) {
      bf16x8_t bfr = __builtin_bit_cast(bf16x8_t, *(const u32x4_t*)(Wb + (ot * 16 + nidx) * 128 + ks * 32 + q * 8));
      accv[ot] = __builtin_amdgcn_mfma_f32_16x16x32_bf16(af, bfr, accv[ot], 0, 0, 0);
    }
  }
#pragma unroll
  for (int ot = 0; ot < 8; ot++) {
    int col = ot * 16 + nidx;
    float bv = bias[col];
    float s = 0.f, sq = 0.f;
#pragma unroll
    for (int j = 0; j < 4; j++) {
      int row = r0 + q * 4 + j;
      if (row < NN) {
        float v = accv[ot][j] + bv;
        u16 h = f2bf(v);
        float vr = bf2f(h);
        H[row * 128 + col] = h;
        s += vr; sq += vr * vr;
      }
    }
    s  += __shfl_xor(s, 16, 64);  s  += __shfl_xor(s, 32, 64);
    sq += __shfl_xor(sq, 16, 64); sq += __shfl_xor(sq, 32, 64);
    if (q == 0) { sst[wave][col] = s; sst[wave][128 + col] = sq; }
  }
  __syncthreads();
  int t = threadIdx.x;
  float tot = sst[0][t] + sst[1][t] + sst[2][t] + sst[3][t];
  atomicAdd(&st[t], tot);
}

// ---------------- fused: BN+ReLU(A) -> GEMM(W2) + stats2 ----------------
__global__ __launch_bounds__(256) void k_bn_gemm(
    const u16* __restrict__ Hin, const u16* __restrict__ Wb, const float* __restrict__ bias,
    const float* __restrict__ st_in, const float* __restrict__ gw, const float* __restrict__ bw,
    u16* __restrict__ Hout, float* __restrict__ st_out) {
  __shared__ float sc[256];
  __shared__ float sst[4][256];
  int t = threadIdx.x;
  if (t < 128) {
    float mu = st_in[t] * (1.0f / NN);
    float var = st_in[128 + t] * (1.0f / NN) - mu * mu;
    var = fmaxf(var, 0.f);
    float r = rsqrtf(var + 1e-5f);
    float scl = gw[t] * r;
    sc[t] = scl;
    sc[128 + t] = bw[t] - mu * scl;
  }
  __syncthreads();
  int wave = t >> 6, lane = t & 63;
  int r0 = blockIdx.x * 64 + wave * 16;
  int nidx = lane & 15, q = lane >> 4;
  int arow = r0 + nidx;
  u32x4_t zero4 = {0, 0, 0, 0};
  u32x4_t raw[4];
#pragma unroll
  for (int ks = 0; ks < 4; ks++)
    raw[ks] = (arow < NN) ? *(const u32x4_t*)(Hin + arow * 128 + ks * 32 + q * 8) : zero4;
  f32x4_t acc[8];
  f32x4_t z4 = {0.f, 0.f, 0.f, 0.f};
#pragma unroll
  for (int ot = 0; ot < 8; ot++) acc[ot] = z4;
#pragma unroll
  for (int ks = 0; ks < 4; ks++) {
    int k0 = ks * 32 + q * 8;
    u32x4_t ap;
#pragma unroll
    for (int w = 0; w < 4; w++) {
      int k = k0 + 2 * w;
      float v0 = fmaxf(bf2f((u16)(raw[ks][w] & 0xffffu)) * sc[k] + sc[128 + k], 0.f);
      float v1 = fmaxf(bf2f((u16)(raw[ks][w] >> 16)) * sc[k + 1] + sc[128 + k + 1], 0.f);
      ap[w] = (u32)f2bf(v0) | ((u32)f2bf(v1) << 16);
    }
    bf16x8_t af = __builtin_bit_cast(bf16x8_t, ap);
#pragma unroll
    for (int ot = 0; ot < 8; ot++) {
      bf16x8_t bfr = __builtin_bit_cast(bf16x8_t, *(const u32x4_t*)(Wb + (ot * 16 + nidx) * 128 + k0));
      acc[ot] = __builtin_amdgcn_mfma_f32_16x16x32_bf16(af, bfr, acc[ot], 0, 0, 0);
    }
  }
#pragma unroll
  for (int ot = 0; ot < 8; ot++) {
    int col = ot * 16 + nidx;
    float bv = bias[col];
    float s = 0.f, sq = 0.f;
#pragma unroll
    for (int j = 0; j < 4; j++) {
      int row = r0 + q * 4 + j;
      if (row < NN) {
        float v = acc[ot][j] + bv;
        u16 h = f2bf(v);
        float vr = bf2f(h);
        Hout[row * 128 + col] = h;
        s += vr; sq += vr * vr;
      }
    }
    s  += __shfl_xor(s, 16, 64);  s  += __shfl_xor(s, 32, 64);
    sq += __shfl_xor(sq, 16, 64); sq += __shfl_xor(sq, 32, 64);
    if (q == 0) { sst[wave][col] = s; sst[wave][128 + col] = sq; }
  }
  __syncthreads();
  float tot = sst[0][t] + sst[1][t] + sst[2][t] + sst[3][t];
  atomicAdd(&st_out[t], tot);
}

// ---------------- fused: BN2+ReLU -> Z_next bf16 + subgraph mean ----------------
__global__ __launch_bounds__(256) void k_bn_sub(
    const u16* __restrict__ Hin, const float* __restrict__ st_in, const float* __restrict__ gw,
    const float* __restrict__ bw, const int* __restrict__ n2s,
    u16* __restrict__ Znext, float* __restrict__ sub, int layer) {
  __shared__ float sc[256];
  int t = threadIdx.x;
  if (t < 128) {
    float mu = st_in[t] * (1.0f / NN);
    float var = st_in[128 + t] * (1.0f / NN) - mu * mu;
    var = fmaxf(var, 0.f);
    float r = rsqrtf(var + 1e-5f);
    float scl = gw[t] * r;
    sc[t] = scl;
    sc[128 + t] = bw[t] - mu * scl;
  }
  __syncthreads();
  int s = (blockIdx.x * 256 + t) >> 6;
  int lane = t & 63;
  if (s >= SS) return;
  int r0 = lbound(n2s, NN, s), r1 = lbound(n2s, NN, s + 1);
  float scl0 = sc[2 * lane], scl1 = sc[2 * lane + 1];
  float sh0 = sc[128 + 2 * lane], sh1 = sc[128 + 2 * lane + 1];
  const u32* hr = (const u32*)Hin;
  u32* zr = (u32*)Znext;
  float a0 = 0.f, a1 = 0.f;
  for (int r = r0; r < r1; r++) {
    u32 d = hr[r * 64 + lane];
    float v0 = fmaxf(bf2f((u16)(d & 0xffffu)) * scl0 + sh0, 0.f);
    float v1 = fmaxf(bf2f((u16)(d >> 16)) * scl1 + sh1, 0.f);
    zr[r * 64 + lane] = (u32)f2bf(v0) | ((u32)f2bf(v1) << 16);
    a0 += v0; a1 += v1;
  }
  int c = r1 - r0;
  float inv = 1.0f / (float)(c > 0 ? c : 1);
  float2 v; v.x = a0 * inv; v.y = a1 * inv;
  *(float2*)(sub + (size_t)s * 512 + layer * 128 + lane * 2) = v;
}

// ---------------- graph mean over subgraphs (sorted segments) ----------------
__global__ __launch_bounds__(256) void k_graphpool(const float* __restrict__ sub, const int* __restrict__ s2g,
                                                   float* __restrict__ gph) {
  int g = (blockIdx.x * 256 + threadIdx.x) >> 6;
  int lane = threadIdx.x & 63;
  if (g >= GG) return;
  int r0 = lbound(s2g, SS, g), r1 = lbound(s2g, SS, g + 1);
  float a[8] = {0.f, 0.f, 0.f, 0.f, 0.f, 0.f, 0.f, 0.f};
  for (int s = r0; s < r1; s++) {
    const float* row = sub + (size_t)s * 512 + lane * 8;
#pragma unroll
    for (int j = 0; j < 8; j++) a[j] += row[j];
  }
  int c = r1 - r0;
  float inv = 1.0f / (float)(c > 0 ? c : 1);
  float* orow = gph + (size_t)g * 512 + lane * 8;
#pragma unroll
  for (int j = 0; j < 8; j++) orow[j] = a[j] * inv;
}

// ---------------- head: lin1+relu, lin2, log_softmax ----------------
__global__ __launch_bounds__(128) void k_head(const float* __restrict__ gph, const float* __restrict__ P,
                                              const int* __restrict__ flagp, void* __restrict__ out) {
  __shared__ float gsh[512];
  __shared__ float hsh[128];
  __shared__ float lsh[12];
  int g = blockIdx.x, t = threadIdx.x;
  for (int i = t; i < 512; i += 128) gsh[i] = gph[(size_t)g * 512 + i];
  __syncthreads();
  float acc = P[O_L1B + t];
  const float4* wr = (const float4*)(P + O_L1W + t * 512);
  for (int kb = 0; kb < 128; kb++) {
    float4 w = wr[kb];
    int k = kb * 4;
    acc += gsh[k] * w.x + gsh[k + 1] * w.y + gsh[k + 2] * w.z + gsh[k + 3] * w.w;
  }
  hsh[t] = fmaxf(acc, 0.f);
  __syncthreads();
  if (t < 10) {
    float a = P[O_L2B + t];
    const float* w2r = P + O_L2W + t * 128;
    for (int k = 0; k < 128; k++) a += hsh[k] * w2r[k];
    lsh[t] = a;
  }
  __syncthreads();
  if (t == 0) {
    float m = -1e30f;
    for (int c = 0; c < 10; c++) m = fmaxf(m, lsh[c]);
    float se = 0.f;
    for (int c = 0; c < 10; c++) se += expf(lsh[c] - m);
    lsh[10] = m + logf(se);
  }
  __syncthreads();
  if (t < 10) {
    float v = lsh[t] - lsh[10];
    if (*flagp) ((float*)out)[g * 10 + t] = v;
    else        ((u16*)out)[g * 10 + t] = f2bf(v);
  }
}

extern "C" void kernel_launch(void* const* d_in, const int* in_sizes, int n_in,
                              void* d_out, int out_size, void* d_ws, size_t ws_size,
                              hipStream_t stream) {
  const void* x   = d_in[0];
  const int* ei   = (const int*)d_in[1];
  const int* n2s  = (const int*)d_in[2];
  const int* s2g  = (const int*)d_in[3];

  char* ws = (char*)d_ws;
  size_t o = 0;
  auto alloc = [&](size_t b) -> void* {
    void* p = ws + o;
    o += (b + 255) & ~(size_t)255;
    return p;
  };
  int* flag   = (int*)alloc(256);
  int* off    = (int*)alloc((NN + 1) * 4);
  int* cnt    = (int*)alloc(NN * 4);
  int* bsum   = (int*)alloc(NSCAN * 4);
  int* csr    = (int*)alloc((size_t)EE * 4);
  u16* zb0    = (u16*)alloc((size_t)NN * 128 * 2);
  u16* zb1    = (u16*)alloc((size_t)NN * 128 * 2);
  u16* H1     = (u16*)alloc((size_t)NN * 128 * 2);
  u16* H2     = (u16*)alloc((size_t)NN * 128 * 2);
  float* sub  = (float*)alloc((size_t)SS * 512 * 4);
  float* gph  = (float*)alloc((size_t)GG * 512 * 4);
  float* stats = (float*)alloc(8 * 256 * 4);
  float* P    = (float*)alloc((size_t)NPAR * 4);
  u16* W1b    = (u16*)alloc(65536 * 2);
  u16* W2b    = (u16*)alloc(65536 * 2);

  const int* esrc = ei;
  const int* edst = ei + EE;

  hipMemsetAsync(cnt, 0, NN * 4, stream);
  hipMemsetAsync(stats, 0, 8 * 256 * 4, stream);

  k_sniff<<<dim3(1), dim3(256), 0, stream>>>((const u16*)x, flag);
  k_cvt_params<<<dim3((NPAR + 255) / 256), dim3(256), 0, stream>>>(
      d_in[4], d_in[5], d_in[6], d_in[7], d_in[8], d_in[9], d_in[10], d_in[11],
      d_in[12], d_in[13], d_in[14], d_in[15], d_in[16], flag, P);
  k_cvtW<<<dim3(512), dim3(256), 0, stream>>>(P, W1b, W2b);
  k_prep<<<dim3((NN * 128 / 8 + 255) / 256), dim3(256), 0, stream>>>(x, flag, zb0);

  k_hist<<<dim3((EE + 255) / 256), dim3(256), 0, stream>>>(edst, cnt);
  k_scan1<<<dim3(NSCAN), dim3(256), 0, stream>>>(cnt, bsum);
  k_scan2<<<dim3(1), dim3(64), 0, stream>>>(bsum, off);
  k_scan3<<<dim3(NSCAN), dim3(256), 0, stream>>>(cnt, bsum, off);
  hipMemsetAsync(cnt, 0, NN * 4, stream);
  k_fill<<<dim3((EE + 255) / 256), dim3(256), 0, stream>>>(esrc, edst, off, cnt, csr);

  for (int l = 0; l < 4; l++) {
    const u16* Zin = (l == 0) ? zb0 : ((l & 1) ? zb1 : zb0);
    u16* Zout = (l & 1) ? zb0 : zb1;
    float* st1 = stats + (2 * l) * 256;
    float* st2 = stats + (2 * l + 1) * 256;
    k_agg_gemm<<<dim3((NN + 63) / 64), dim3(256), 0, stream>>>(
        Zin, off, csr, W1b + l * 16384, P + O_B1 + l * 128, P, l, H1, st1);
    k_bn_gemm<<<dim3((NN + 63) / 64), dim3(256), 0, stream>>>(
        H1, W2b + l * 16384, P + O_B2 + l * 128, st1, P + O_G1 + l * 128, P + O_BE1 + l * 128, H2, st2);
    k_bn_sub<<<dim3((SS + 3) / 4), dim3(256), 0, stream>>>(
        H2, st2, P + O_G2 + l * 128, P + O_BE2 + l * 128, n2s, Zout, sub, l);
  }
  k_graphpool<<<dim3((GG + 3) / 4), dim3(256), 0, stream>>>(sub, s2g, gph);
  k_head<<<dim3(GG), dim3(128), 0, stream>>>(gph, P, flag, (void*)d_out);
}

// Round 2
// 1393.459 us; speedup vs baseline: 4.0223x; 4.0223x over previous
//
#include <hip/hip_runtime.h>

typedef unsigned int u32;
typedef unsigned short u16;

#define NN 100000
#define EE 1600000
#define SS 10000
#define GG 256
#define NSCAN ((NN + 1023) / 1024)

// param block offsets (f32 elements)
#define O_W1   0
#define O_B1   65536
#define O_G1   66048
#define O_BE1  66560
#define O_W2   67072
#define O_B2   132608
#define O_G2   133120
#define O_BE2  133632
#define O_EPS  134144
#define O_L1W  134148
#define O_L1B  199684
#define O_L2W  199812
#define O_L2B  201092
#define NPAR   201102

typedef __bf16 bf16x8_t __attribute__((ext_vector_type(8)));
typedef float f32x4_t __attribute__((ext_vector_type(4)));
typedef u32 u32x4_t __attribute__((ext_vector_type(4)));

__device__ __forceinline__ float bf2f(u16 u) {
  union { u32 i; float f; } x; x.i = ((u32)u) << 16; return x.f;
}
__device__ __forceinline__ u16 f2bf(float f) {
  union { float f; u32 i; } x; x.f = f;
  u32 r = x.i + 0x7fffu + ((x.i >> 16) & 1u);
  return (u16)(r >> 16);
}
__device__ __forceinline__ int lbound(const int* __restrict__ a, int n, int key) {
  int lo = 0, hi = n;
  while (lo < hi) { int mid = (lo + hi) >> 1; if (a[mid] < key) lo = mid + 1; else hi = mid; }
  return lo;
}

// ---------------- dtype sniff: 1 = inputs are f32, 0 = bf16 ----------------
__global__ void k_sniff(const u16* __restrict__ x, int* __restrict__ flag) {
  __shared__ int cnt;
  if (threadIdx.x == 0) cnt = 0;
  __syncthreads();
  int weird = 0;
  for (int i = threadIdx.x; i < 8192; i += 256) {
    u16 v = x[i];
    int e = (v >> 7) & 0xff;
    if (e >= 0xC0) weird++;
  }
  atomicAdd(&cnt, weird);
  __syncthreads();
  if (threadIdx.x == 0) *flag = (cnt > 64) ? 1 : 0;
}

// ---------------- convert all params into f32 block P ----------------
__global__ __launch_bounds__(256) void k_cvt_params(
    const void* pW1, const void* pb1, const void* pg1, const void* pbe1,
    const void* pW2, const void* pb2, const void* pg2, const void* pbe2,
    const void* peps, const void* pl1w, const void* pl1b, const void* pl2w, const void* pl2b,
    const int* __restrict__ flagp, float* __restrict__ P) {
  int i = blockIdx.x * 256 + threadIdx.x;
  if (i >= NPAR) return;
  const void* src; int rel;
  if      (i < O_B1)  { src = pW1;  rel = i - O_W1; }
  else if (i < O_G1)  { src = pb1;  rel = i - O_B1; }
  else if (i < O_BE1) { src = pg1;  rel = i - O_G1; }
  else if (i < O_W2)  { src = pbe1; rel = i - O_BE1; }
  else if (i < O_B2)  { src = pW2;  rel = i - O_W2; }
  else if (i < O_G2)  { src = pb2;  rel = i - O_B2; }
  else if (i < O_BE2) { src = pg2;  rel = i - O_G2; }
  else if (i < O_EPS) { src = pbe2; rel = i - O_BE2; }
  else if (i < O_L1W) { src = peps; rel = i - O_EPS; }
  else if (i < O_L1B) { src = pl1w; rel = i - O_L1W; }
  else if (i < O_L2W) { src = pl1b; rel = i - O_L1B; }
  else if (i < O_L2B) { src = pl2w; rel = i - O_L2W; }
  else                { src = pl2b; rel = i - O_L2B; }
  float v = (*flagp) ? ((const float*)src)[rel] : bf2f(((const u16*)src)[rel]);
  P[i] = v;
}

// ---------------- W1/W2 -> bf16 ----------------
__global__ __launch_bounds__(256) void k_cvtW(const float* __restrict__ P,
                                              u16* __restrict__ W1b, u16* __restrict__ W2b) {
  int i = blockIdx.x * 256 + threadIdx.x;
  if (i >= 131072) return;
  if (i < 65536) W1b[i] = f2bf(P[O_W1 + i]);
  else           W2b[i - 65536] = f2bf(P[O_W2 + i - 65536]);
}

// ---------------- x -> Z0 bf16 ----------------
__global__ __launch_bounds__(256) void k_prep(const void* __restrict__ x, const int* __restrict__ flagp,
                                              u16* __restrict__ Z0) {
  int i = blockIdx.x * 256 + threadIdx.x;
  if (i >= (NN * 128) / 8) return;
  if (*flagp) {
    const float4* xf = (const float4*)x;
    float4 a = xf[i * 2], b = xf[i * 2 + 1];
    u32x4_t o;
    o[0] = (u32)f2bf(a.x) | ((u32)f2bf(a.y) << 16);
    o[1] = (u32)f2bf(a.z) | ((u32)f2bf(a.w) << 16);
    o[2] = (u32)f2bf(b.x) | ((u32)f2bf(b.y) << 16);
    o[3] = (u32)f2bf(b.z) | ((u32)f2bf(b.w) << 16);
    *(u32x4_t*)(Z0 + i * 8) = o;
  } else {
    *(u32x4_t*)(Z0 + i * 8) = ((const u32x4_t*)x)[i];
  }
}

// ---------------- CSR build ----------------
__global__ __launch_bounds__(256) void k_hist(const int* __restrict__ dst, int* __restrict__ cnt) {
  int i = blockIdx.x * 256 + threadIdx.x;
  if (i < EE) atomicAdd(&cnt[dst[i]], 1);
}

__global__ __launch_bounds__(256) void k_scan1(const int* __restrict__ cnt, int* __restrict__ bsum) {
  __shared__ int sh[256];
  int base = blockIdx.x * 1024 + threadIdx.x * 4;
  int s = 0;
#pragma unroll
  for (int i = 0; i < 4; i++) { int idx = base + i; s += (idx < NN) ? cnt[idx] : 0; }
  sh[threadIdx.x] = s; __syncthreads();
  for (int o = 128; o > 0; o >>= 1) {
    if (threadIdx.x < o) sh[threadIdx.x] += sh[threadIdx.x + o];
    __syncthreads();
  }
  if (threadIdx.x == 0) bsum[blockIdx.x] = sh[0];
}

__global__ void k_scan2(int* __restrict__ bsum, int* __restrict__ off) {
  if (threadIdx.x == 0 && blockIdx.x == 0) {
    int run = 0;
    for (int i = 0; i < NSCAN; i++) { int v = bsum[i]; bsum[i] = run; run += v; }
    off[NN] = run;
  }
}

__global__ __launch_bounds__(256) void k_scan3(const int* __restrict__ cnt, const int* __restrict__ bsum,
                                               int* __restrict__ off) {
  __shared__ int sh[256];
  int base = blockIdx.x * 1024 + threadIdx.x * 4;
  int v[4]; int s = 0;
#pragma unroll
  for (int i = 0; i < 4; i++) { int idx = base + i; v[i] = (idx < NN) ? cnt[idx] : 0; s += v[i]; }
  sh[threadIdx.x] = s; __syncthreads();
  for (int o = 1; o < 256; o <<= 1) {
    int add = (threadIdx.x >= o) ? sh[threadIdx.x - o] : 0;
    __syncthreads();
    sh[threadIdx.x] += add;
    __syncthreads();
  }
  int run = sh[threadIdx.x] - s + bsum[blockIdx.x];
#pragma unroll
  for (int i = 0; i < 4; i++) { int idx = base + i; if (idx < NN) { off[idx] = run; run += v[i]; } }
}

__global__ __launch_bounds__(256) void k_fill(const int* __restrict__ src, const int* __restrict__ dst,
                                              const int* __restrict__ off, int* __restrict__ cur,
                                              int* __restrict__ csr) {
  int i = blockIdx.x * 256 + threadIdx.x;
  if (i >= EE) return;
  int d = dst[i];
  int p = off[d] + atomicAdd(&cur[d], 1);
  csr[p] = src[i];
}

// ---------------- fused: gather-agg -> LDS -> GEMM(W1) + stats1 ----------------
// Round-0 structure (register accumulation per row), ONE change: gather inner loop
// is 16-wide with dual-bank software pipelining (issue batch B before consuming A),
// halving exposed vmcnt drains per row. Static indexing throughout (no scratch).
#define LD16(D, ip_, off_)                                     \
  {                                                            \
    _Pragma("unroll") for (int j = 0; j < 16; j++)             \
        D[j] = zr[(u32)(ip_)[(off_) + j] * 64u + lane];        \
  }
#define CS16(D)                                                \
  {                                                            \
    _Pragma("unroll") for (int j = 0; j < 16; j++) {           \
      a0 += bf2f((u16)(D[j] & 0xffffu));                       \
      a1 += bf2f((u16)(D[j] >> 16));                           \
    }                                                          \
  }
__global__ __launch_bounds__(256) void k_agg_gemm(
    const u16* __restrict__ Z, const int* __restrict__ off, const int* __restrict__ csr,
    const u16* __restrict__ Wb, const float* __restrict__ bias, const float* __restrict__ P,
    int layer, u16* __restrict__ H, float* __restrict__ st) {
  __shared__ __align__(16) u16 lds[4][16][136];
  __shared__ __align__(16) int shidx[4][512];   // idx staging; aliased as stats slice later
  int wave = threadIdx.x >> 6, lane = threadIdx.x & 63;
  int r0 = blockIdx.x * 64 + wave * 16;
  float ev = 1.0f + P[O_EPS + layer];
  const u32* zr = (const u32*)Z;

  // prefetch off[r0 .. r0+16] (clamped) via lanes 0..16
  int offv = 0;
  if (lane <= 16) {
    int rr = r0 + lane; if (rr > NN) rr = NN; if (rr < 0) rr = 0;
    offv = off[rr];
  }
  int ebase = __shfl(offv, 0, 64);
  int eend  = __shfl(offv, 16, 64);
  int tn = eend - ebase;
  int nst = tn < 512 ? tn : 512;
  // stage neighbor indices (coalesced, wave-private region -> no barrier)
  for (int i = lane; i < nst; i += 64) shidx[wave][i] = csr[ebase + i];

  for (int rr = 0; rr < 16; rr++) {
    int row = r0 + rr;
    float a0 = 0.f, a1 = 0.f;
    if (row < NN) {
      int s = __shfl(offv, rr, 64), e = __shfl(offv, rr + 1, 64);
      int n = e - s, b = s - ebase;
      u32 d = zr[row * 64 + lane];
      a0 = ev * bf2f((u16)(d & 0xffffu));
      a1 = ev * bf2f((u16)(d >> 16));
      const int* ip = (b + n <= 512) ? &shidx[wave][b] : &csr[s];
      int nb = n >> 4;                 // full 16-batches
      int i = nb << 4;
      if (nb > 0) {
        u32 dA[16], dB[16];
        LD16(dA, ip, 0);
        int bb = 1;
        for (; bb + 1 < nb; bb += 2) {
          LD16(dB, ip, bb * 16); CS16(dA);
          LD16(dA, ip, (bb + 1) * 16); CS16(dB);
        }
        if (bb < nb) { LD16(dB, ip, bb * 16); CS16(dA); CS16(dB); }
        else         { CS16(dA); }
      }
      // tail (up to 15 edges)
      for (; i + 1 < n; i += 2) {
        u32 d0 = zr[(u32)ip[i] * 64u + lane];
        u32 d1 = zr[(u32)ip[i + 1] * 64u + lane];
        a0 += bf2f((u16)(d0 & 0xffffu)) + bf2f((u16)(d1 & 0xffffu));
        a1 += bf2f((u16)(d0 >> 16)) + bf2f((u16)(d1 >> 16));
      }
      if (i < n) {
        u32 d0 = zr[(u32)ip[i] * 64u + lane];
        a0 += bf2f((u16)(d0 & 0xffffu));
        a1 += bf2f((u16)(d0 >> 16));
      }
    }
    ((u32*)&lds[wave][rr][0])[lane] = (u32)f2bf(a0) | ((u32)f2bf(a1) << 16);
  }

  // MFMA over the wave-private tile (no barrier needed)
  int nidx = lane & 15, q = lane >> 4;
  f32x4_t acc[8];
  f32x4_t z4 = {0.f, 0.f, 0.f, 0.f};
#pragma unroll
  for (int ot = 0; ot < 8; ot++) acc[ot] = z4;
#pragma unroll
  for (int ks = 0; ks < 4; ks++) {
    bf16x8_t af = __builtin_bit_cast(bf16x8_t, *(const u32x4_t*)&lds[wave][nidx][ks * 32 + q * 8]);
#pragma unroll
    for (int ot = 0; ot < 8; ot++) {
      bf16x8_t bfr = __builtin_bit_cast(bf16x8_t, *(const u32x4_t*)(Wb + (ot * 16 + nidx) * 128 + ks * 32 + q * 8));
      acc[ot] = __builtin_amdgcn_mfma_f32_16x16x32_bf16(af, bfr, acc[ot], 0, 0, 0);
    }
  }
  float* sstw = (float*)&shidx[wave][0];  // done with this wave's idx region
#pragma unroll
  for (int ot = 0; ot < 8; ot++) {
    int col = ot * 16 + nidx;
    float bv = bias[col];
    float s = 0.f, sq = 0.f;
#pragma unroll
    for (int j = 0; j < 4; j++) {
      int row = r0 + q * 4 + j;
      if (row < NN) {
        float v = acc[ot][j] + bv;
        u16 h = f2bf(v);
        float vr = bf2f(h);
        H[row * 128 + col] = h;
        s += vr; sq += vr * vr;
      }
    }
    s  += __shfl_xor(s, 16, 64);  s  += __shfl_xor(s, 32, 64);
    sq += __shfl_xor(sq, 16, 64); sq += __shfl_xor(sq, 32, 64);
    if (q == 0) { sstw[col] = s; sstw[128 + col] = sq; }
  }
  __syncthreads();
  int t = threadIdx.x;
  float tot = ((float*)&shidx[0][0])[t] + ((float*)&shidx[1][0])[t] +
              ((float*)&shidx[2][0])[t] + ((float*)&shidx[3][0])[t];
  atomicAdd(&st[t], tot);
}

// ---------------- fused: BN+ReLU(A) -> GEMM(W2) + stats2 ----------------
__global__ __launch_bounds__(256) void k_bn_gemm(
    const u16* __restrict__ Hin, const u16* __restrict__ Wb, const float* __restrict__ bias,
    const float* __restrict__ st_in, const float* __restrict__ gw, const float* __restrict__ bw,
    u16* __restrict__ Hout, float* __restrict__ st_out) {
  __shared__ float sc[256];
  __shared__ float sst[4][256];
  int t = threadIdx.x;
  if (t < 128) {
    float mu = st_in[t] * (1.0f / NN);
    float var = st_in[128 + t] * (1.0f / NN) - mu * mu;
    var = fmaxf(var, 0.f);
    float r = rsqrtf(var + 1e-5f);
    float scl = gw[t] * r;
    sc[t] = scl;
    sc[128 + t] = bw[t] - mu * scl;
  }
  __syncthreads();
  int wave = t >> 6, lane = t & 63;
  int r0 = blockIdx.x * 64 + wave * 16;
  int nidx = lane & 15, q = lane >> 4;
  int arow = r0 + nidx;
  u32x4_t zero4 = {0, 0, 0, 0};
  u32x4_t raw[4];
#pragma unroll
  for (int ks = 0; ks < 4; ks++)
    raw[ks] = (arow < NN) ? *(const u32x4_t*)(Hin + arow * 128 + ks * 32 + q * 8) : zero4;
  f32x4_t acc[8];
  f32x4_t z4 = {0.f, 0.f, 0.f, 0.f};
#pragma unroll
  for (int ot = 0; ot < 8; ot++) acc[ot] = z4;
#pragma unroll
  for (int ks = 0; ks < 4; ks++) {
    int k0 = ks * 32 + q * 8;
    u32x4_t ap;
#pragma unroll
    for (int w = 0; w < 4; w++) {
      int k = k0 + 2 * w;
      float v0 = fmaxf(bf2f((u16)(raw[ks][w] & 0xffffu)) * sc[k] + sc[128 + k], 0.f);
      float v1 = fmaxf(bf2f((u16)(raw[ks][w] >> 16)) * sc[k + 1] + sc[128 + k + 1], 0.f);
      ap[w] = (u32)f2bf(v0) | ((u32)f2bf(v1) << 16);
    }
    bf16x8_t af = __builtin_bit_cast(bf16x8_t, ap);
#pragma unroll
    for (int ot = 0; ot < 8; ot++) {
      bf16x8_t bfr = __builtin_bit_cast(bf16x8_t, *(const u32x4_t*)(Wb + (ot * 16 + nidx) * 128 + k0));
      acc[ot] = __builtin_amdgcn_mfma_f32_16x16x32_bf16(af, bfr, acc[ot], 0, 0, 0);
    }
  }
#pragma unroll
  for (int ot = 0; ot < 8; ot++) {
    int col = ot * 16 + nidx;
    float bv = bias[col];
    float s = 0.f, sq = 0.f;
#pragma unroll
    for (int j = 0; j < 4; j++) {
      int row = r0 + q * 4 + j;
      if (row < NN) {
        float v = acc[ot][j] + bv;
        u16 h = f2bf(v);
        float vr = bf2f(h);
        Hout[row * 128 + col] = h;
        s += vr; sq += vr * vr;
      }
    }
    s  += __shfl_xor(s, 16, 64);  s  += __shfl_xor(s, 32, 64);
    sq += __shfl_xor(sq, 16, 64); sq += __shfl_xor(sq, 32, 64);
    if (q == 0) { sst[wave][col] = s; sst[wave][128 + col] = sq; }
  }
  __syncthreads();
  float tot = sst[0][t] + sst[1][t] + sst[2][t] + sst[3][t];
  atomicAdd(&st_out[t], tot);
}

// ---------------- fused: BN2+ReLU -> Z_next bf16 + subgraph mean ----------------
__global__ __launch_bounds__(256) void k_bn_sub(
    const u16* __restrict__ Hin, const float* __restrict__ st_in, const float* __restrict__ gw,
    const float* __restrict__ bw, const int* __restrict__ n2s,
    u16* __restrict__ Znext, float* __restrict__ sub, int layer) {
  __shared__ float sc[256];
  int t = threadIdx.x;
  if (t < 128) {
    float mu = st_in[t] * (1.0f / NN);
    float var = st_in[128 + t] * (1.0f / NN) - mu * mu;
    var = fmaxf(var, 0.f);
    float r = rsqrtf(var + 1e-5f);
    float scl = gw[t] * r;
    sc[t] = scl;
    sc[128 + t] = bw[t] - mu * scl;
  }
  __syncthreads();
  int s = (blockIdx.x * 256 + t) >> 6;
  int lane = t & 63;
  if (s >= SS) return;
  int r0 = lbound(n2s, NN, s), r1 = lbound(n2s, NN, s + 1);
  float scl0 = sc[2 * lane], scl1 = sc[2 * lane + 1];
  float sh0 = sc[128 + 2 * lane], sh1 = sc[128 + 2 * lane + 1];
  const u32* hr = (const u32*)Hin;
  u32* zr = (u32*)Znext;
  float a0 = 0.f, a1 = 0.f;
  for (int r = r0; r < r1; r++) {
    u32 d = hr[r * 64 + lane];
    float v0 = fmaxf(bf2f((u16)(d & 0xffffu)) * scl0 + sh0, 0.f);
    float v1 = fmaxf(bf2f((u16)(d >> 16)) * scl1 + sh1, 0.f);
    zr[r * 64 + lane] = (u32)f2bf(v0) | ((u32)f2bf(v1) << 16);
    a0 += v0; a1 += v1;
  }
  int c = r1 - r0;
  float inv = 1.0f / (float)(c > 0 ? c : 1);
  float2 v; v.x = a0 * inv; v.y = a1 * inv;
  *(float2*)(sub + (size_t)s * 512 + layer * 128 + lane * 2) = v;
}

// ---------------- graph mean over subgraphs (sorted segments) ----------------
__global__ __launch_bounds__(256) void k_graphpool(const float* __restrict__ sub, const int* __restrict__ s2g,
                                                   float* __restrict__ gph) {
  int g = (blockIdx.x * 256 + threadIdx.x) >> 6;
  int lane = threadIdx.x & 63;
  if (g >= GG) return;
  int r0 = lbound(s2g, SS, g), r1 = lbound(s2g, SS, g + 1);
  float a[8] = {0.f, 0.f, 0.f, 0.f, 0.f, 0.f, 0.f, 0.f};
  for (int s = r0; s < r1; s++) {
    const float* row = sub + (size_t)s * 512 + lane * 8;
#pragma unroll
    for (int j = 0; j < 8; j++) a[j] += row[j];
  }
  int c = r1 - r0;
  float inv = 1.0f / (float)(c > 0 ? c : 1);
  float* orow = gph + (size_t)g * 512 + lane * 8;
#pragma unroll
  for (int j = 0; j < 8; j++) orow[j] = a[j] * inv;
}

// ---------------- head: lin1+relu, lin2, log_softmax ----------------
__global__ __launch_bounds__(128) void k_head(const float* __restrict__ gph, const float* __restrict__ P,
                                              const int* __restrict__ flagp, void* __restrict__ out) {
  __shared__ float gsh[512];
  __shared__ float hsh[128];
  __shared__ float lsh[12];
  int g = blockIdx.x, t = threadIdx.x;
  for (int i = t; i < 512; i += 128) gsh[i] = gph[(size_t)g * 512 + i];
  __syncthreads();
  float acc = P[O_L1B + t];
  const float4* wr = (const float4*)(P + O_L1W + t * 512);
  for (int kb = 0; kb < 128; kb++) {
    float4 w = wr[kb];
    int k = kb * 4;
    acc += gsh[k] * w.x + gsh[k + 1] * w.y + gsh[k + 2] * w.z + gsh[k + 3] * w.w;
  }
  hsh[t] = fmaxf(acc, 0.f);
  __syncthreads();
  if (t < 10) {
    float a = P[O_L2B + t];
    const float* w2r = P + O_L2W + t * 128;
    for (int k = 0; k < 128; k++) a += hsh[k] * w2r[k];
    lsh[t] = a;
  }
  __syncthreads();
  if (t == 0) {
    float m = -1e30f;
    for (int c = 0; c < 10; c++) m = fmaxf(m, lsh[c]);
    float se = 0.f;
    for (int c = 0; c < 10; c++) se += expf(lsh[c] - m);
    lsh[10] = m + logf(se);
  }
  __syncthreads();
  if (t < 10) {
    float v = lsh[t] - lsh[10];
    if (*flagp) ((float*)out)[g * 10 + t] = v;
    else        ((u16*)out)[g * 10 + t] = f2bf(v);
  }
}

extern "C" void kernel_launch(void* const* d_in, const int* in_sizes, int n_in,
                              void* d_out, int out_size, void* d_ws, size_t ws_size,
                              hipStream_t stream) {
  const void* x   = d_in[0];
  const int* ei   = (const int*)d_in[1];
  const int* n2s  = (const int*)d_in[2];
  const int* s2g  = (const int*)d_in[3];

  char* ws = (char*)d_ws;
  size_t o = 0;
  auto alloc = [&](size_t b) -> void* {
    void* p = ws + o;
    o += (b + 255) & ~(size_t)255;
    return p;
  };
  int* flag   = (int*)alloc(256);
  int* off    = (int*)alloc((NN + 1) * 4);
  int* cnt    = (int*)alloc(NN * 4);
  int* bsum   = (int*)alloc(NSCAN * 4);
  int* csr    = (int*)alloc((size_t)EE * 4);
  u16* zb0    = (u16*)alloc((size_t)NN * 128 * 2);
  u16* zb1    = (u16*)alloc((size_t)NN * 128 * 2);
  u16* H1     = (u16*)alloc((size_t)NN * 128 * 2);
  u16* H2     = (u16*)alloc((size_t)NN * 128 * 2);
  float* sub  = (float*)alloc((size_t)SS * 512 * 4);
  float* gph  = (float*)alloc((size_t)GG * 512 * 4);
  float* stats = (float*)alloc(8 * 256 * 4);
  float* P    = (float*)alloc((size_t)NPAR * 4);
  u16* W1b    = (u16*)alloc(65536 * 2);
  u16* W2b    = (u16*)alloc(65536 * 2);

  const int* esrc = ei;
  const int* edst = ei + EE;

  hipMemsetAsync(cnt, 0, NN * 4, stream);
  hipMemsetAsync(stats, 0, 8 * 256 * 4, stream);

  k_sniff<<<dim3(1), dim3(256), 0, stream>>>((const u16*)x, flag);
  k_cvt_params<<<dim3((NPAR + 255) / 256), dim3(256), 0, stream>>>(
      d_in[4], d_in[5], d_in[6], d_in[7], d_in[8], d_in[9], d_in[10], d_in[11],
      d_in[12], d_in[13], d_in[14], d_in[15], d_in[16], flag, P);
  k_cvtW<<<dim3(512), dim3(256), 0, stream>>>(P, W1b, W2b);
  k_prep<<<dim3((NN * 128 / 8 + 255) / 256), dim3(256), 0, stream>>>(x, flag, zb0);

  k_hist<<<dim3((EE + 255) / 256), dim3(256), 0, stream>>>(edst, cnt);
  k_scan1<<<dim3(NSCAN), dim3(256), 0, stream>>>(cnt, bsum);
  k_scan2<<<dim3(1), dim3(64), 0, stream>>>(bsum, off);
  k_scan3<<<dim3(NSCAN), dim3(256), 0, stream>>>(cnt, bsum, off);
  hipMemsetAsync(cnt, 0, NN * 4, stream);
  k_fill<<<dim3((EE + 255) / 256), dim3(256), 0, stream>>>(esrc, edst, off, cnt, csr);

  for (int l = 0; l < 4; l++) {
    const u16* Zin = (l == 0) ? zb0 : ((l & 1) ? zb1 : zb0);
    u16* Zout = (l & 1) ? zb0 : zb1;
    float* st1 = stats + (2 * l) * 256;
    float* st2 = stats + (2 * l + 1) * 256;
    k_agg_gemm<<<dim3((NN + 63) / 64), dim3(256), 0, stream>>>(
        Zin, off, csr, W1b + l * 16384, P + O_B1 + l * 128, P, l, H1, st1);
    k_bn_gemm<<<dim3((NN + 63) / 64), dim3(256), 0, stream>>>(
        H1, W2b + l * 16384, P + O_B2 + l * 128, st1, P + O_G1 + l * 128, P + O_BE1 + l * 128, H2, st2);
    k_bn_sub<<<dim3((SS + 3) / 4), dim3(256), 0, stream>>>(
        H2, st2, P + O_G2 + l * 128, P + O_BE2 + l * 128, n2s, Zout, sub, l);
  }
  k_graphpool<<<dim3((GG + 3) / 4), dim3(256), 0, stream>>>(sub, s2g, gph);
  k_head<<<dim3(GG), dim3(128), 0, stream>>>(gph, P, flag, (void*)d_out);
}

// Round 4
// 1329.287 us; speedup vs baseline: 4.2165x; 1.0483x over previous
//
#include <hip/hip_runtime.h>

typedef unsigned int u32;
typedef unsigned short u16;

#define NN 100000
#define EE 1600000
#define SS 10000
#define GG 256
#define NSCAN ((NN + 1023) / 1024)

// param block offsets (f32 elements)
#define O_W1   0
#define O_B1   65536
#define O_G1   66048
#define O_BE1  66560
#define O_W2   67072
#define O_B2   132608
#define O_G2   133120
#define O_BE2  133632
#define O_EPS  134144
#define O_L1W  134148
#define O_L1B  199684
#define O_L2W  199812
#define O_L2B  201092
#define NPAR   201102

typedef __bf16 bf16x8_t __attribute__((ext_vector_type(8)));
typedef float f32x4_t __attribute__((ext_vector_type(4)));
typedef u32 u32x4_t __attribute__((ext_vector_type(4)));

__device__ __forceinline__ float bf2f(u16 u) {
  union { u32 i; float f; } x; x.i = ((u32)u) << 16; return x.f;
}
__device__ __forceinline__ u16 f2bf(float f) {
  union { float f; u32 i; } x; x.f = f;
  u32 r = x.i + 0x7fffu + ((x.i >> 16) & 1u);
  return (u16)(r >> 16);
}
__device__ __forceinline__ int lbound(const int* __restrict__ a, int n, int key) {
  int lo = 0, hi = n;
  while (lo < hi) { int mid = (lo + hi) >> 1; if (a[mid] < key) lo = mid + 1; else hi = mid; }
  return lo;
}

// ---------------- dtype sniff: 1 = inputs are f32, 0 = bf16 ----------------
__global__ void k_sniff(const u16* __restrict__ x, int* __restrict__ flag) {
  __shared__ int cnt;
  if (threadIdx.x == 0) cnt = 0;
  __syncthreads();
  int weird = 0;
  for (int i = threadIdx.x; i < 8192; i += 256) {
    u16 v = x[i];
    int e = (v >> 7) & 0xff;
    if (e >= 0xC0) weird++;
  }
  atomicAdd(&cnt, weird);
  __syncthreads();
  if (threadIdx.x == 0) *flag = (cnt > 64) ? 1 : 0;
}

// ---------------- convert all params into f32 block P ----------------
__global__ __launch_bounds__(256) void k_cvt_params(
    const void* pW1, const void* pb1, const void* pg1, const void* pbe1,
    const void* pW2, const void* pb2, const void* pg2, const void* pbe2,
    const void* peps, const void* pl1w, const void* pl1b, const void* pl2w, const void* pl2b,
    const int* __restrict__ flagp, float* __restrict__ P) {
  int i = blockIdx.x * 256 + threadIdx.x;
  if (i >= NPAR) return;
  const void* src; int rel;
  if      (i < O_B1)  { src = pW1;  rel = i - O_W1; }
  else if (i < O_G1)  { src = pb1;  rel = i - O_B1; }
  else if (i < O_BE1) { src = pg1;  rel = i - O_G1; }
  else if (i < O_W2)  { src = pbe1; rel = i - O_BE1; }
  else if (i < O_B2)  { src = pW2;  rel = i - O_W2; }
  else if (i < O_G2)  { src = pb2;  rel = i - O_B2; }
  else if (i < O_BE2) { src = pg2;  rel = i - O_G2; }
  else if (i < O_EPS) { src = pbe2; rel = i - O_BE2; }
  else if (i < O_L1W) { src = peps; rel = i - O_EPS; }
  else if (i < O_L1B) { src = pl1w; rel = i - O_L1W; }
  else if (i < O_L2W) { src = pl1b; rel = i - O_L1B; }
  else if (i < O_L2B) { src = pl2w; rel = i - O_L2W; }
  else                { src = pl2b; rel = i - O_L2B; }
  float v = (*flagp) ? ((const float*)src)[rel] : bf2f(((const u16*)src)[rel]);
  P[i] = v;
}

// ---------------- W1/W2 -> bf16 ----------------
__global__ __launch_bounds__(256) void k_cvtW(const float* __restrict__ P,
                                              u16* __restrict__ W1b, u16* __restrict__ W2b) {
  int i = blockIdx.x * 256 + threadIdx.x;
  if (i >= 131072) return;
  if (i < 65536) W1b[i] = f2bf(P[O_W1 + i]);
  else           W2b[i - 65536] = f2bf(P[O_W2 + i - 65536]);
}

// ---------------- x -> Z0 bf16 ----------------
__global__ __launch_bounds__(256) void k_prep(const void* __restrict__ x, const int* __restrict__ flagp,
                                              u16* __restrict__ Z0) {
  int i = blockIdx.x * 256 + threadIdx.x;
  if (i >= (NN * 128) / 8) return;
  if (*flagp) {
    const float4* xf = (const float4*)x;
    float4 a = xf[i * 2], b = xf[i * 2 + 1];
    u32x4_t o;
    o[0] = (u32)f2bf(a.x) | ((u32)f2bf(a.y) << 16);
    o[1] = (u32)f2bf(a.z) | ((u32)f2bf(a.w) << 16);
    o[2] = (u32)f2bf(b.x) | ((u32)f2bf(b.y) << 16);
    o[3] = (u32)f2bf(b.z) | ((u32)f2bf(b.w) << 16);
    *(u32x4_t*)(Z0 + i * 8) = o;
  } else {
    *(u32x4_t*)(Z0 + i * 8) = ((const u32x4_t*)x)[i];
  }
}

// ---------------- CSR build ----------------
__global__ __launch_bounds__(256) void k_hist(const int* __restrict__ dst, int* __restrict__ cnt) {
  int i = blockIdx.x * 256 + threadIdx.x;
  if (i < EE) atomicAdd(&cnt[dst[i]], 1);
}

__global__ __launch_bounds__(256) void k_scan1(const int* __restrict__ cnt, int* __restrict__ bsum) {
  __shared__ int sh[256];
  int base = blockIdx.x * 1024 + threadIdx.x * 4;
  int s = 0;
#pragma unroll
  for (int i = 0; i < 4; i++) { int idx = base + i; s += (idx < NN) ? cnt[idx] : 0; }
  sh[threadIdx.x] = s; __syncthreads();
  for (int o = 128; o > 0; o >>= 1) {
    if (threadIdx.x < o) sh[threadIdx.x] += sh[threadIdx.x + o];
    __syncthreads();
  }
  if (threadIdx.x == 0) bsum[blockIdx.x] = sh[0];
}

__global__ void k_scan2(int* __restrict__ bsum, int* __restrict__ off) {
  if (threadIdx.x == 0 && blockIdx.x == 0) {
    int run = 0;
    for (int i = 0; i < NSCAN; i++) { int v = bsum[i]; bsum[i] = run; run += v; }
    off[NN] = run;
  }
}

__global__ __launch_bounds__(256) void k_scan3(const int* __restrict__ cnt, const int* __restrict__ bsum,
                                               int* __restrict__ off) {
  __shared__ int sh[256];
  int base = blockIdx.x * 1024 + threadIdx.x * 4;
  int v[4]; int s = 0;
#pragma unroll
  for (int i = 0; i < 4; i++) { int idx = base + i; v[i] = (idx < NN) ? cnt[idx] : 0; s += v[i]; }
  sh[threadIdx.x] = s; __syncthreads();
  for (int o = 1; o < 256; o <<= 1) {
    int add = (threadIdx.x >= o) ? sh[threadIdx.x - o] : 0;
    __syncthreads();
    sh[threadIdx.x] += add;
    __syncthreads();
  }
  int run = sh[threadIdx.x] - s + bsum[blockIdx.x];
#pragma unroll
  for (int i = 0; i < 4; i++) { int idx = base + i; if (idx < NN) { off[idx] = run; run += v[i]; } }
}

__global__ __launch_bounds__(256) void k_fill(const int* __restrict__ src, const int* __restrict__ dst,
                                              const int* __restrict__ off, int* __restrict__ cur,
                                              int* __restrict__ csr) {
  int i = blockIdx.x * 256 + threadIdx.x;
  if (i >= EE) return;
  int d = dst[i];
  int p = off[d] + atomicAdd(&cur[d], 1);
  csr[p] = src[i];
}

// ---------------- fused: gather-agg -> LDS -> GEMM(W1) + stats1 ----------------
// Round-0 code path EXACTLY; one variable changed: block reshaped 4 waves -> 2 waves
// (128 threads, 32 rows, 12.8 KB LDS) to double resident-wave ceiling per CU.
// Occupancy A/B: latency-bound hypothesis predicts ~proportional speedup.
__global__ __launch_bounds__(128) void k_agg_gemm(
    const u16* __restrict__ Z, const int* __restrict__ off, const int* __restrict__ csr,
    const u16* __restrict__ Wb, const float* __restrict__ bias, const float* __restrict__ P,
    int layer, u16* __restrict__ H, float* __restrict__ st) {
  __shared__ __align__(16) u16 lds[2][16][136];
  __shared__ __align__(16) int shidx[2][512];   // idx staging; aliased as stats slice later
  int wave = threadIdx.x >> 6, lane = threadIdx.x & 63;
  int r0 = blockIdx.x * 32 + wave * 16;
  float ev = 1.0f + P[O_EPS + layer];
  const u32* zr = (const u32*)Z;

  // prefetch off[r0 .. r0+16] (clamped) via lanes 0..16
  int offv = 0;
  if (lane <= 16) {
    int rr = r0 + lane; if (rr > NN) rr = NN; if (rr < 0) rr = 0;
    offv = off[rr];
  }
  int ebase = __shfl(offv, 0, 64);
  int eend  = __shfl(offv, 16, 64);
  int tn = eend - ebase;
  int nst = tn < 512 ? tn : 512;
  // stage neighbor indices (coalesced, wave-private region -> no barrier)
  for (int i = lane; i < nst; i += 64) shidx[wave][i] = csr[ebase + i];

  for (int rr = 0; rr < 16; rr++) {
    int row = r0 + rr;
    float a0 = 0.f, a1 = 0.f;
    if (row < NN) {
      int s = __shfl(offv, rr, 64), e = __shfl(offv, rr + 1, 64);
      int n = e - s, b = s - ebase;
      u32 d = zr[row * 64 + lane];
      a0 = ev * bf2f((u16)(d & 0xffffu));
      a1 = ev * bf2f((u16)(d >> 16));
      const int* ip = (b + n <= 512) ? &shidx[wave][b] : &csr[s];
      int i = 0;
      for (; i + 7 < n; i += 8) {
        u32 dd[8];
#pragma unroll
        for (int j = 0; j < 8; j++) dd[j] = zr[ip[i + j] * 64 + lane];
#pragma unroll
        for (int j = 0; j < 8; j++) {
          a0 += bf2f((u16)(dd[j] & 0xffffu));
          a1 += bf2f((u16)(dd[j] >> 16));
        }
      }
      for (; i + 1 < n; i += 2) {
        u32 d0 = zr[ip[i] * 64 + lane];
        u32 d1 = zr[ip[i + 1] * 64 + lane];
        a0 += bf2f((u16)(d0 & 0xffffu)) + bf2f((u16)(d1 & 0xffffu));
        a1 += bf2f((u16)(d0 >> 16)) + bf2f((u16)(d1 >> 16));
      }
      if (i < n) {
        u32 d0 = zr[ip[i] * 64 + lane];
        a0 += bf2f((u16)(d0 & 0xffffu));
        a1 += bf2f((u16)(d0 >> 16));
      }
    }
    ((u32*)&lds[wave][rr][0])[lane] = (u32)f2bf(a0) | ((u32)f2bf(a1) << 16);
  }

  // MFMA over the wave-private tile (no barrier needed)
  int nidx = lane & 15, q = lane >> 4;
  f32x4_t acc[8];
  f32x4_t z4 = {0.f, 0.f, 0.f, 0.f};
#pragma unroll
  for (int ot = 0; ot < 8; ot++) acc[ot] = z4;
#pragma unroll
  for (int ks = 0; ks < 4; ks++) {
    bf16x8_t af = __builtin_bit_cast(bf16x8_t, *(const u32x4_t*)&lds[wave][nidx][ks * 32 + q * 8]);
#pragma unroll
    for (int ot = 0; ot < 8; ot++) {
      bf16x8_t bfr = __builtin_bit_cast(bf16x8_t, *(const u32x4_t*)(Wb + (ot * 16 + nidx) * 128 + ks * 32 + q * 8));
      acc[ot] = __builtin_amdgcn_mfma_f32_16x16x32_bf16(af, bfr, acc[ot], 0, 0, 0);
    }
  }
  float* sstw = (float*)&shidx[wave][0];  // done with this wave's idx region
#pragma unroll
  for (int ot = 0; ot < 8; ot++) {
    int col = ot * 16 + nidx;
    float bv = bias[col];
    float s = 0.f, sq = 0.f;
#pragma unroll
    for (int j = 0; j < 4; j++) {
      int row = r0 + q * 4 + j;
      if (row < NN) {
        float v = acc[ot][j] + bv;
        u16 h = f2bf(v);
        float vr = bf2f(h);
        H[row * 128 + col] = h;
        s += vr; sq += vr * vr;
      }
    }
    s  += __shfl_xor(s, 16, 64);  s  += __shfl_xor(s, 32, 64);
    sq += __shfl_xor(sq, 16, 64); sq += __shfl_xor(sq, 32, 64);
    if (q == 0) { sstw[col] = s; sstw[128 + col] = sq; }
  }
  __syncthreads();
  int t = threadIdx.x;
  float tot0 = ((float*)&shidx[0][0])[t] + ((float*)&shidx[1][0])[t];
  float tot1 = ((float*)&shidx[0][0])[t + 128] + ((float*)&shidx[1][0])[t + 128];
  atomicAdd(&st[t], tot0);
  atomicAdd(&st[t + 128], tot1);
}

// ---------------- fused: BN+ReLU(A) -> GEMM(W2) + stats2 ----------------
__global__ __launch_bounds__(256) void k_bn_gemm(
    const u16* __restrict__ Hin, const u16* __restrict__ Wb, const float* __restrict__ bias,
    const float* __restrict__ st_in, const float* __restrict__ gw, const float* __restrict__ bw,
    u16* __restrict__ Hout, float* __restrict__ st_out) {
  __shared__ float sc[256];
  __shared__ float sst[4][256];
  int t = threadIdx.x;
  if (t < 128) {
    float mu = st_in[t] * (1.0f / NN);
    float var = st_in[128 + t] * (1.0f / NN) - mu * mu;
    var = fmaxf(var, 0.f);
    float r = rsqrtf(var + 1e-5f);
    float scl = gw[t] * r;
    sc[t] = scl;
    sc[128 + t] = bw[t] - mu * scl;
  }
  __syncthreads();
  int wave = t >> 6, lane = t & 63;
  int r0 = blockIdx.x * 64 + wave * 16;
  int nidx = lane & 15, q = lane >> 4;
  int arow = r0 + nidx;
  u32x4_t zero4 = {0, 0, 0, 0};
  u32x4_t raw[4];
#pragma unroll
  for (int ks = 0; ks < 4; ks++)
    raw[ks] = (arow < NN) ? *(const u32x4_t*)(Hin + arow * 128 + ks * 32 + q * 8) : zero4;
  f32x4_t acc[8];
  f32x4_t z4 = {0.f, 0.f, 0.f, 0.f};
#pragma unroll
  for (int ot = 0; ot < 8; ot++) acc[ot] = z4;
#pragma unroll
  for (int ks = 0; ks < 4; ks++) {
    int k0 = ks * 32 + q * 8;
    u32x4_t ap;
#pragma unroll
    for (int w = 0; w < 4; w++) {
      int k = k0 + 2 * w;
      float v0 = fmaxf(bf2f((u16)(raw[ks][w] & 0xffffu)) * sc[k] + sc[128 + k], 0.f);
      float v1 = fmaxf(bf2f((u16)(raw[ks][w] >> 16)) * sc[k + 1] + sc[128 + k + 1], 0.f);
      ap[w] = (u32)f2bf(v0) | ((u32)f2bf(v1) << 16);
    }
    bf16x8_t af = __builtin_bit_cast(bf16x8_t, ap);
#pragma unroll
    for (int ot = 0; ot < 8; ot++) {
      bf16x8_t bfr = __builtin_bit_cast(bf16x8_t, *(const u32x4_t*)(Wb + (ot * 16 + nidx) * 128 + k0));
      acc[ot] = __builtin_amdgcn_mfma_f32_16x16x32_bf16(af, bfr, acc[ot], 0, 0, 0);
    }
  }
#pragma unroll
  for (int ot = 0; ot < 8; ot++) {
    int col = ot * 16 + nidx;
    float bv = bias[col];
    float s = 0.f, sq = 0.f;
#pragma unroll
    for (int j = 0; j < 4; j++) {
      int row = r0 + q * 4 + j;
      if (row < NN) {
        float v = acc[ot][j] + bv;
        u16 h = f2bf(v);
        float vr = bf2f(h);
        Hout[row * 128 + col] = h;
        s += vr; sq += vr * vr;
      }
    }
    s  += __shfl_xor(s, 16, 64);  s  += __shfl_xor(s, 32, 64);
    sq += __shfl_xor(sq, 16, 64); sq += __shfl_xor(sq, 32, 64);
    if (q == 0) { sst[wave][col] = s; sst[wave][128 + col] = sq; }
  }
  __syncthreads();
  float tot = sst[0][t] + sst[1][t] + sst[2][t] + sst[3][t];
  atomicAdd(&st_out[t], tot);
}

// ---------------- fused: BN2+ReLU -> Z_next bf16 + subgraph mean ----------------
__global__ __launch_bounds__(256) void k_bn_sub(
    const u16* __restrict__ Hin, const float* __restrict__ st_in, const float* __restrict__ gw,
    const float* __restrict__ bw, const int* __restrict__ n2s,
    u16* __restrict__ Znext, float* __restrict__ sub, int layer) {
  __shared__ float sc[256];
  int t = threadIdx.x;
  if (t < 128) {
    float mu = st_in[t] * (1.0f / NN);
    float var = st_in[128 + t] * (1.0f / NN) - mu * mu;
    var = fmaxf(var, 0.f);
    float r = rsqrtf(var + 1e-5f);
    float scl = gw[t] * r;
    sc[t] = scl;
    sc[128 + t] = bw[t] - mu * scl;
  }
  __syncthreads();
  int s = (blockIdx.x * 256 + t) >> 6;
  int lane = t & 63;
  if (s >= SS) return;
  int r0 = lbound(n2s, NN, s), r1 = lbound(n2s, NN, s + 1);
  float scl0 = sc[2 * lane], scl1 = sc[2 * lane + 1];
  float sh0 = sc[128 + 2 * lane], sh1 = sc[128 + 2 * lane + 1];
  const u32* hr = (const u32*)Hin;
  u32* zr = (u32*)Znext;
  float a0 = 0.f, a1 = 0.f;
  for (int r = r0; r < r1; r++) {
    u32 d = hr[r * 64 + lane];
    float v0 = fmaxf(bf2f((u16)(d & 0xffffu)) * scl0 + sh0, 0.f);
    float v1 = fmaxf(bf2f((u16)(d >> 16)) * scl1 + sh1, 0.f);
    zr[r * 64 + lane] = (u32)f2bf(v0) | ((u32)f2bf(v1) << 16);
    a0 += v0; a1 += v1;
  }
  int c = r1 - r0;
  float inv = 1.0f / (float)(c > 0 ? c : 1);
  float2 v; v.x = a0 * inv; v.y = a1 * inv;
  *(float2*)(sub + (size_t)s * 512 + layer * 128 + lane * 2) = v;
}

// ---------------- graph mean over subgraphs (sorted segments) ----------------
__global__ __launch_bounds__(256) void k_graphpool(const float* __restrict__ sub, const int* __restrict__ s2g,
                                                   float* __restrict__ gph) {
  int g = (blockIdx.x * 256 + threadIdx.x) >> 6;
  int lane = threadIdx.x & 63;
  if (g >= GG) return;
  int r0 = lbound(s2g, SS, g), r1 = lbound(s2g, SS, g + 1);
  float a[8] = {0.f, 0.f, 0.f, 0.f, 0.f, 0.f, 0.f, 0.f};
  for (int s = r0; s < r1; s++) {
    const float* row = sub + (size_t)s * 512 + lane * 8;
#pragma unroll
    for (int j = 0; j < 8; j++) a[j] += row[j];
  }
  int c = r1 - r0;
  float inv = 1.0f / (float)(c > 0 ? c : 1);
  float* orow = gph + (size_t)g * 512 + lane * 8;
#pragma unroll
  for (int j = 0; j < 8; j++) orow[j] = a[j] * inv;
}

// ---------------- head: lin1+relu, lin2, log_softmax ----------------
__global__ __launch_bounds__(128) void k_head(const float* __restrict__ gph, const float* __restrict__ P,
                                              const int* __restrict__ flagp, void* __restrict__ out) {
  __shared__ float gsh[512];
  __shared__ float hsh[128];
  __shared__ float lsh[12];
  int g = blockIdx.x, t = threadIdx.x;
  for (int i = t; i < 512; i += 128) gsh[i] = gph[(size_t)g * 512 + i];
  __syncthreads();
  float acc = P[O_L1B + t];
  const float4* wr = (const float4*)(P + O_L1W + t * 512);
  for (int kb = 0; kb < 128; kb++) {
    float4 w = wr[kb];
    int k = kb * 4;
    acc += gsh[k] * w.x + gsh[k + 1] * w.y + gsh[k + 2] * w.z + gsh[k + 3] * w.w;
  }
  hsh[t] = fmaxf(acc, 0.f);
  __syncthreads();
  if (t < 10) {
    float a = P[O_L2B + t];
    const float* w2r = P + O_L2W + t * 128;
    for (int k = 0; k < 128; k++) a += hsh[k] * w2r[k];
    lsh[t] = a;
  }
  __syncthreads();
  if (t == 0) {
    float m = -1e30f;
    for (int c = 0; c < 10; c++) m = fmaxf(m, lsh[c]);
    float se = 0.f;
    for (int c = 0; c < 10; c++) se += expf(lsh[c] - m);
    lsh[10] = m + logf(se);
  }
  __syncthreads();
  if (t < 10) {
    float v = lsh[t] - lsh[10];
    if (*flagp) ((float*)out)[g * 10 + t] = v;
    else        ((u16*)out)[g * 10 + t] = f2bf(v);
  }
}

extern "C" void kernel_launch(void* const* d_in, const int* in_sizes, int n_in,
                              void* d_out, int out_size, void* d_ws, size_t ws_size,
                              hipStream_t stream) {
  const void* x   = d_in[0];
  const int* ei   = (const int*)d_in[1];
  const int* n2s  = (const int*)d_in[2];
  const int* s2g  = (const int*)d_in[3];

  char* ws = (char*)d_ws;
  size_t o = 0;
  auto alloc = [&](size_t b) -> void* {
    void* p = ws + o;
    o += (b + 255) & ~(size_t)255;
    return p;
  };
  int* flag   = (int*)alloc(256);
  int* off    = (int*)alloc((NN + 1) * 4);
  int* cnt    = (int*)alloc(NN * 4);
  int* bsum   = (int*)alloc(NSCAN * 4);
  int* csr    = (int*)alloc((size_t)EE * 4);
  u16* zb0    = (u16*)alloc((size_t)NN * 128 * 2);
  u16* zb1    = (u16*)alloc((size_t)NN * 128 * 2);
  u16* H1     = (u16*)alloc((size_t)NN * 128 * 2);
  u16* H2     = (u16*)alloc((size_t)NN * 128 * 2);
  float* sub  = (float*)alloc((size_t)SS * 512 * 4);
  float* gph  = (float*)alloc((size_t)GG * 512 * 4);
  float* stats = (float*)alloc(8 * 256 * 4);
  float* P    = (float*)alloc((size_t)NPAR * 4);
  u16* W1b    = (u16*)alloc(65536 * 2);
  u16* W2b    = (u16*)alloc(65536 * 2);

  const int* esrc = ei;
  const int* edst = ei + EE;

  hipMemsetAsync(cnt, 0, NN * 4, stream);
  hipMemsetAsync(stats, 0, 8 * 256 * 4, stream);

  k_sniff<<<dim3(1), dim3(256), 0, stream>>>((const u16*)x, flag);
  k_cvt_params<<<dim3((NPAR + 255) / 256), dim3(256), 0, stream>>>(
      d_in[4], d_in[5], d_in[6], d_in[7], d_in[8], d_in[9], d_in[10], d_in[11],
      d_in[12], d_in[13], d_in[14], d_in[15], d_in[16], flag, P);
  k_cvtW<<<dim3(512), dim3(256), 0, stream>>>(P, W1b, W2b);
  k_prep<<<dim3((NN * 128 / 8 + 255) / 256), dim3(256), 0, stream>>>(x, flag, zb0);

  k_hist<<<dim3((EE + 255) / 256), dim3(256), 0, stream>>>(edst, cnt);
  k_scan1<<<dim3(NSCAN), dim3(256), 0, stream>>>(cnt, bsum);
  k_scan2<<<dim3(1), dim3(64), 0, stream>>>(bsum, off);
  k_scan3<<<dim3(NSCAN), dim3(256), 0, stream>>>(cnt, bsum, off);
  hipMemsetAsync(cnt, 0, NN * 4, stream);
  k_fill<<<dim3((EE + 255) / 256), dim3(256), 0, stream>>>(esrc, edst, off, cnt, csr);

  for (int l = 0; l < 4; l++) {
    const u16* Zin = (l == 0) ? zb0 : ((l & 1) ? zb1 : zb0);
    u16* Zout = (l & 1) ? zb0 : zb1;
    float* st1 = stats + (2 * l) * 256;
    float* st2 = stats + (2 * l + 1) * 256;
    k_agg_gemm<<<dim3((NN + 31) / 32), dim3(128), 0, stream>>>(
        Zin, off, csr, W1b + l * 16384, P + O_B1 + l * 128, P, l, H1, st1);
    k_bn_gemm<<<dim3((NN + 63) / 64), dim3(256), 0, stream>>>(
        H1, W2b + l * 16384, P + O_B2 + l * 128, st1, P + O_G1 + l * 128, P + O_BE1 + l * 128, H2, st2);
    k_bn_sub<<<dim3((SS + 3) / 4), dim3(256), 0, stream>>>(
        H2, st2, P + O_G2 + l * 128, P + O_BE2 + l * 128, n2s, Zout, sub, l);
  }
  k_graphpool<<<dim3((GG + 3) / 4), dim3(256), 0, stream>>>(sub, s2g, gph);
  k_head<<<dim3(GG), dim3(128), 0, stream>>>(gph, P, flag, (void*)d_out);
}

// Round 5
// 1186.048 us; speedup vs baseline: 4.7257x; 1.1208x over previous
//
#include <hip/hip_runtime.h>

typedef unsigned int u32;
typedef unsigned short u16;

#define NN 100000
#define EE 1600000
#define SS 10000
#define GG 256
#define NSCAN ((NN + 1023) / 1024)

// param block offsets (f32 elements)
#define O_W1   0
#define O_B1   65536
#define O_G1   66048
#define O_BE1  66560
#define O_W2   67072
#define O_B2   132608
#define O_G2   133120
#define O_BE2  133632
#define O_EPS  134144
#define O_L1W  134148
#define O_L1B  199684
#define O_L2W  199812
#define O_L2B  201092
#define NPAR   201102

typedef __bf16 bf16x8_t __attribute__((ext_vector_type(8)));
typedef float f32x4_t __attribute__((ext_vector_type(4)));
typedef u32 u32x4_t __attribute__((ext_vector_type(4)));

__device__ __forceinline__ float bf2f(u16 u) {
  union { u32 i; float f; } x; x.i = ((u32)u) << 16; return x.f;
}
__device__ __forceinline__ u16 f2bf(float f) {
  union { float f; u32 i; } x; x.f = f;
  u32 r = x.i + 0x7fffu + ((x.i >> 16) & 1u);
  return (u16)(r >> 16);
}
__device__ __forceinline__ int lbound(const int* __restrict__ a, int n, int key) {
  int lo = 0, hi = n;
  while (lo < hi) { int mid = (lo + hi) >> 1; if (a[mid] < key) lo = mid + 1; else hi = mid; }
  return lo;
}

// local dtype sniff: counts u16 "exponent" bytes >= 0xC0 over 1024 elems.
// f32 input -> mantissa-random low halves -> ~128 hits; bf16 -> ~0 hits.
__device__ __forceinline__ int local_sniff(const u16* x16, int t, int nthr, int* swc) {
  int w = 0;
  int per = 1024 / nthr;
  for (int k = 0; k < per; k++) {
    u16 v = x16[t + k * nthr];
    if (((v >> 7) & 0xff) >= 0xC0) w++;
  }
  atomicAdd(swc, w);
  __syncthreads();
  return (*swc > 16) ? 1 : 0;
}

// ---------------- fused setup: sniff + param cvt + W cvt + x->Z0 + hist ----------------
__global__ __launch_bounds__(256) void k_setup(
    const void* __restrict__ x, const int* __restrict__ edst,
    const void* pW1, const void* pb1, const void* pg1, const void* pbe1,
    const void* pW2, const void* pb2, const void* pg2, const void* pbe2,
    const void* peps, const void* pl1w, const void* pl1b, const void* pl2w, const void* pl2b,
    float* __restrict__ P, u16* __restrict__ W1b, u16* __restrict__ W2b,
    u16* __restrict__ Z0, int* __restrict__ cnt) {
  __shared__ int swc;
  int t = threadIdx.x, b = blockIdx.x;
  if (t == 0) swc = 0;
  __syncthreads();
  int flag = local_sniff((const u16*)x, t, 256, &swc);

  // prep: x -> Z0 bf16, 8 elems per thread (grid covers exactly NN*128/8)
  int i = b * 256 + t;
  if (i < (NN * 128) / 8) {
    if (flag) {
      const float4* xf = (const float4*)x;
      float4 va = xf[i * 2], vb = xf[i * 2 + 1];
      u32x4_t o;
      o[0] = (u32)f2bf(va.x) | ((u32)f2bf(va.y) << 16);
      o[1] = (u32)f2bf(va.z) | ((u32)f2bf(va.w) << 16);
      o[2] = (u32)f2bf(vb.x) | ((u32)f2bf(vb.y) << 16);
      o[3] = (u32)f2bf(vb.z) | ((u32)f2bf(vb.w) << 16);
      *(u32x4_t*)(Z0 + i * 8) = o;
    } else {
      *(u32x4_t*)(Z0 + i * 8) = ((const u32x4_t*)x)[i];
    }
  }

  // W1/W2 -> bf16 directly from source (skip P round-trip)
  if (b < 512) {
    int j = b * 256 + t;
    if (j < 65536) W1b[j] = flag ? f2bf(((const float*)pW1)[j]) : ((const u16*)pW1)[j];
    else { int j2 = j - 65536; W2b[j2] = flag ? f2bf(((const float*)pW2)[j2]) : ((const u16*)pW2)[j2]; }
  } else if (b < 786) {
    // P tail: [O_B1,O_W2) (1536) then [O_B2,NPAR) (68494) -> 70030 elems
    int j = (b - 512) * 256 + t;
    if (j < 70030) {
      int i2 = (j < 1536) ? (O_B1 + j) : (O_B2 + (j - 1536));
      const void* src; int rel;
      if      (i2 < O_G1)  { src = pb1;  rel = i2 - O_B1; }
      else if (i2 < O_BE1) { src = pg1;  rel = i2 - O_G1; }
      else if (i2 < O_W2)  { src = pbe1; rel = i2 - O_BE1; }
      else if (i2 < O_G2)  { src = pb2;  rel = i2 - O_B2; }
      else if (i2 < O_BE2) { src = pg2;  rel = i2 - O_G2; }
      else if (i2 < O_EPS) { src = pbe2; rel = i2 - O_BE2; }
      else if (i2 < O_L1W) { src = peps; rel = i2 - O_EPS; }
      else if (i2 < O_L1B) { src = pl1w; rel = i2 - O_L1W; }
      else if (i2 < O_L2W) { src = pl1b; rel = i2 - O_L1B; }
      else if (i2 < O_L2B) { src = pl2w; rel = i2 - O_L2W; }
      else                 { src = pl2b; rel = i2 - O_L2B; }
      P[i2] = flag ? ((const float*)src)[rel] : bf2f(((const u16*)src)[rel]);
    }
  }

  // hist (cnt pre-zeroed by memset before this kernel)
  int e = b * 256 + t;
  if (e < EE) atomicAdd(&cnt[edst[e]], 1);
}

// ---------------- CSR build ----------------
__global__ __launch_bounds__(256) void k_scan1(const int* __restrict__ cnt, int* __restrict__ bsum) {
  __shared__ int sh[256];
  int base = blockIdx.x * 1024 + threadIdx.x * 4;
  int s = 0;
#pragma unroll
  for (int i = 0; i < 4; i++) { int idx = base + i; s += (idx < NN) ? cnt[idx] : 0; }
  sh[threadIdx.x] = s; __syncthreads();
  for (int o = 128; o > 0; o >>= 1) {
    if (threadIdx.x < o) sh[threadIdx.x] += sh[threadIdx.x + o];
    __syncthreads();
  }
  if (threadIdx.x == 0) bsum[blockIdx.x] = sh[0];
}

// scan3 with inlined block-prefix of bsum (kills scan2 + its dependency)
__global__ __launch_bounds__(256) void k_scan3x(const int* __restrict__ cnt, const int* __restrict__ bsum,
                                                int* __restrict__ off) {
  __shared__ int sh[256];
  __shared__ int bpre;
  if (threadIdx.x < 64) {
    int l = threadIdx.x;
    int v = 0;
    if (l < blockIdx.x && l < NSCAN) v += bsum[l];
    if (l + 64 < blockIdx.x && l + 64 < NSCAN) v += bsum[l + 64];
    for (int o = 1; o < 64; o <<= 1) v += __shfl_xor(v, o, 64);
    if (l == 0) bpre = v;
  }
  int base = blockIdx.x * 1024 + threadIdx.x * 4;
  int v4[4]; int s = 0;
#pragma unroll
  for (int i = 0; i < 4; i++) { int idx = base + i; v4[i] = (idx < NN) ? cnt[idx] : 0; s += v4[i]; }
  sh[threadIdx.x] = s; __syncthreads();
  for (int o = 1; o < 256; o <<= 1) {
    int add = (threadIdx.x >= o) ? sh[threadIdx.x - o] : 0;
    __syncthreads();
    sh[threadIdx.x] += add;
    __syncthreads();
  }
  int run = sh[threadIdx.x] - s + bpre;
#pragma unroll
  for (int i = 0; i < 4; i++) {
    int idx = base + i;
    if (idx < NN) { off[idx] = run; run += v4[i]; if (idx == NN - 1) off[NN] = run; }
  }
}

__global__ __launch_bounds__(256) void k_fill(const int* __restrict__ src, const int* __restrict__ dst,
                                              const int* __restrict__ off, int* __restrict__ cur,
                                              int* __restrict__ csr) {
  int i = blockIdx.x * 256 + threadIdx.x;
  if (i >= EE) return;
  int d = dst[i];
  int p = off[d] + atomicAdd(&cur[d], 1);
  csr[p] = src[i];
}

// ---------------- fused: gather-agg -> LDS -> GEMM(W1) + stats1 (round-0 form) ----------------
__global__ __launch_bounds__(256) void k_agg_gemm(
    const u16* __restrict__ Z, const int* __restrict__ off, const int* __restrict__ csr,
    const u16* __restrict__ Wb, const float* __restrict__ bias, const float* __restrict__ P,
    int layer, u16* __restrict__ H, float* __restrict__ st) {
  __shared__ __align__(16) u16 lds[4][16][136];
  __shared__ __align__(16) int shidx[4][512];   // idx staging; aliased as stats slice later
  int wave = threadIdx.x >> 6, lane = threadIdx.x & 63;
  int r0 = blockIdx.x * 64 + wave * 16;
  float ev = 1.0f + P[O_EPS + layer];
  const u32* zr = (const u32*)Z;

  int offv = 0;
  if (lane <= 16) {
    int rr = r0 + lane; if (rr > NN) rr = NN; if (rr < 0) rr = 0;
    offv = off[rr];
  }
  int ebase = __shfl(offv, 0, 64);
  int eend  = __shfl(offv, 16, 64);
  int tn = eend - ebase;
  int nst = tn < 512 ? tn : 512;
  for (int i = lane; i < nst; i += 64) shidx[wave][i] = csr[ebase + i];

  for (int rr = 0; rr < 16; rr++) {
    int row = r0 + rr;
    float a0 = 0.f, a1 = 0.f;
    if (row < NN) {
      int s = __shfl(offv, rr, 64), e = __shfl(offv, rr + 1, 64);
      int n = e - s, b = s - ebase;
      u32 d = zr[row * 64 + lane];
      a0 = ev * bf2f((u16)(d & 0xffffu));
      a1 = ev * bf2f((u16)(d >> 16));
      const int* ip = (b + n <= 512) ? &shidx[wave][b] : &csr[s];
      int i = 0;
      for (; i + 7 < n; i += 8) {
        u32 dd[8];
#pragma unroll
        for (int j = 0; j < 8; j++) dd[j] = zr[ip[i + j] * 64 + lane];
#pragma unroll
        for (int j = 0; j < 8; j++) {
          a0 += bf2f((u16)(dd[j] & 0xffffu));
          a1 += bf2f((u16)(dd[j] >> 16));
        }
      }
      for (; i + 1 < n; i += 2) {
        u32 d0 = zr[ip[i] * 64 + lane];
        u32 d1 = zr[ip[i + 1] * 64 + lane];
        a0 += bf2f((u16)(d0 & 0xffffu)) + bf2f((u16)(d1 & 0xffffu));
        a1 += bf2f((u16)(d0 >> 16)) + bf2f((u16)(d1 >> 16));
      }
      if (i < n) {
        u32 d0 = zr[ip[i] * 64 + lane];
        a0 += bf2f((u16)(d0 & 0xffffu));
        a1 += bf2f((u16)(d0 >> 16));
      }
    }
    ((u32*)&lds[wave][rr][0])[lane] = (u32)f2bf(a0) | ((u32)f2bf(a1) << 16);
  }

  int nidx = lane & 15, q = lane >> 4;
  f32x4_t acc[8];
  f32x4_t z4 = {0.f, 0.f, 0.f, 0.f};
#pragma unroll
  for (int ot = 0; ot < 8; ot++) acc[ot] = z4;
#pragma unroll
  for (int ks = 0; ks < 4; ks++) {
    bf16x8_t af = __builtin_bit_cast(bf16x8_t, *(const u32x4_t*)&lds[wave][nidx][ks * 32 + q * 8]);
#pragma unroll
    for (int ot = 0; ot < 8; ot++) {
      bf16x8_t bfr = __builtin_bit_cast(bf16x8_t, *(const u32x4_t*)(Wb + (ot * 16 + nidx) * 128 + ks * 32 + q * 8));
      acc[ot] = __builtin_amdgcn_mfma_f32_16x16x32_bf16(af, bfr, acc[ot], 0, 0, 0);
    }
  }
  float* sstw = (float*)&shidx[wave][0];
#pragma unroll
  for (int ot = 0; ot < 8; ot++) {
    int col = ot * 16 + nidx;
    float bv = bias[col];
    float s = 0.f, sq = 0.f;
#pragma unroll
    for (int j = 0; j < 4; j++) {
      int row = r0 + q * 4 + j;
      if (row < NN) {
        float v = acc[ot][j] + bv;
        u16 h = f2bf(v);
        float vr = bf2f(h);
        H[row * 128 + col] = h;
        s += vr; sq += vr * vr;
      }
    }
    s  += __shfl_xor(s, 16, 64);  s  += __shfl_xor(s, 32, 64);
    sq += __shfl_xor(sq, 16, 64); sq += __shfl_xor(sq, 32, 64);
    if (q == 0) { sstw[col] = s; sstw[128 + col] = sq; }
  }
  __syncthreads();
  int t = threadIdx.x;
  float tot = ((float*)&shidx[0][0])[t] + ((float*)&shidx[1][0])[t] +
              ((float*)&shidx[2][0])[t] + ((float*)&shidx[3][0])[t];
  atomicAdd(&st[t], tot);
}

// ---------------- fused: BN+ReLU(A) -> GEMM(W2) + stats2 ----------------
__global__ __launch_bounds__(256) void k_bn_gemm(
    const u16* __restrict__ Hin, const u16* __restrict__ Wb, const float* __restrict__ bias,
    const float* __restrict__ st_in, const float* __restrict__ gw, const float* __restrict__ bw,
    u16* __restrict__ Hout, float* __restrict__ st_out) {
  __shared__ float sc[256];
  __shared__ float sst[4][256];
  int t = threadIdx.x;
  if (t < 128) {
    float mu = st_in[t] * (1.0f / NN);
    float var = st_in[128 + t] * (1.0f / NN) - mu * mu;
    var = fmaxf(var, 0.f);
    float r = rsqrtf(var + 1e-5f);
    float scl = gw[t] * r;
    sc[t] = scl;
    sc[128 + t] = bw[t] - mu * scl;
  }
  __syncthreads();
  int wave = t >> 6, lane = t & 63;
  int r0 = blockIdx.x * 64 + wave * 16;
  int nidx = lane & 15, q = lane >> 4;
  int arow = r0 + nidx;
  u32x4_t zero4 = {0, 0, 0, 0};
  u32x4_t raw[4];
#pragma unroll
  for (int ks = 0; ks < 4; ks++)
    raw[ks] = (arow < NN) ? *(const u32x4_t*)(Hin + arow * 128 + ks * 32 + q * 8) : zero4;
  f32x4_t acc[8];
  f32x4_t z4 = {0.f, 0.f, 0.f, 0.f};
#pragma unroll
  for (int ot = 0; ot < 8; ot++) acc[ot] = z4;
#pragma unroll
  for (int ks = 0; ks < 4; ks++) {
    int k0 = ks * 32 + q * 8;
    u32x4_t ap;
#pragma unroll
    for (int w = 0; w < 4; w++) {
      int k = k0 + 2 * w;
      float v0 = fmaxf(bf2f((u16)(raw[ks][w] & 0xffffu)) * sc[k] + sc[128 + k], 0.f);
      float v1 = fmaxf(bf2f((u16)(raw[ks][w] >> 16)) * sc[k + 1] + sc[128 + k + 1], 0.f);
      ap[w] = (u32)f2bf(v0) | ((u32)f2bf(v1) << 16);
    }
    bf16x8_t af = __builtin_bit_cast(bf16x8_t, ap);
#pragma unroll
    for (int ot = 0; ot < 8; ot++) {
      bf16x8_t bfr = __builtin_bit_cast(bf16x8_t, *(const u32x4_t*)(Wb + (ot * 16 + nidx) * 128 + k0));
      acc[ot] = __builtin_amdgcn_mfma_f32_16x16x32_bf16(af, bfr, acc[ot], 0, 0, 0);
    }
  }
#pragma unroll
  for (int ot = 0; ot < 8; ot++) {
    int col = ot * 16 + nidx;
    float bv = bias[col];
    float s = 0.f, sq = 0.f;
#pragma unroll
    for (int j = 0; j < 4; j++) {
      int row = r0 + q * 4 + j;
      if (row < NN) {
        float v = acc[ot][j] + bv;
        u16 h = f2bf(v);
        float vr = bf2f(h);
        Hout[row * 128 + col] = h;
        s += vr; sq += vr * vr;
      }
    }
    s  += __shfl_xor(s, 16, 64);  s  += __shfl_xor(s, 32, 64);
    sq += __shfl_xor(sq, 16, 64); sq += __shfl_xor(sq, 32, 64);
    if (q == 0) { sst[wave][col] = s; sst[wave][128 + col] = sq; }
  }
  __syncthreads();
  float tot = sst[0][t] + sst[1][t] + sst[2][t] + sst[3][t];
  atomicAdd(&st_out[t], tot);
}

// ---------------- fused: BN2+ReLU -> Z_next bf16 + subgraph mean ----------------
__global__ __launch_bounds__(256) void k_bn_sub(
    const u16* __restrict__ Hin, const float* __restrict__ st_in, const float* __restrict__ gw,
    const float* __restrict__ bw, const int* __restrict__ n2s,
    u16* __restrict__ Znext, float* __restrict__ sub, int layer) {
  __shared__ float sc[256];
  int t = threadIdx.x;
  if (t < 128) {
    float mu = st_in[t] * (1.0f / NN);
    float var = st_in[128 + t] * (1.0f / NN) - mu * mu;
    var = fmaxf(var, 0.f);
    float r = rsqrtf(var + 1e-5f);
    float scl = gw[t] * r;
    sc[t] = scl;
    sc[128 + t] = bw[t] - mu * scl;
  }
  __syncthreads();
  int s = (blockIdx.x * 256 + t) >> 6;
  int lane = t & 63;
  if (s >= SS) return;
  int r0 = lbound(n2s, NN, s), r1 = lbound(n2s, NN, s + 1);
  float scl0 = sc[2 * lane], scl1 = sc[2 * lane + 1];
  float sh0 = sc[128 + 2 * lane], sh1 = sc[128 + 2 * lane + 1];
  const u32* hr = (const u32*)Hin;
  u32* zr = (u32*)Znext;
  float a0 = 0.f, a1 = 0.f;
  for (int r = r0; r < r1; r++) {
    u32 d = hr[r * 64 + lane];
    float v0 = fmaxf(bf2f((u16)(d & 0xffffu)) * scl0 + sh0, 0.f);
    float v1 = fmaxf(bf2f((u16)(d >> 16)) * scl1 + sh1, 0.f);
    zr[r * 64 + lane] = (u32)f2bf(v0) | ((u32)f2bf(v1) << 16);
    a0 += v0; a1 += v1;
  }
  int c = r1 - r0;
  float inv = 1.0f / (float)(c > 0 ? c : 1);
  float2 v; v.x = a0 * inv; v.y = a1 * inv;
  *(float2*)(sub + (size_t)s * 512 + layer * 128 + lane * 2) = v;
}

// ---------------- fused: graph mean + head (block per graph) ----------------
__global__ __launch_bounds__(128) void k_poolhead(const float* __restrict__ sub, const int* __restrict__ s2g,
                                                  const float* __restrict__ P, const void* __restrict__ x,
                                                  void* __restrict__ out) {
  __shared__ float gsh[512];
  __shared__ float hsh[128];
  __shared__ float lsh[12];
  __shared__ int swc;
  int g = blockIdx.x, t = threadIdx.x;
  if (t == 0) swc = 0;
  __syncthreads();
  int flag = local_sniff((const u16*)x, t, 128, &swc);

  // pool: mean over this graph's subgraph rows
  int r0 = lbound(s2g, SS, g), r1 = lbound(s2g, SS, g + 1);
  float4 a = {0.f, 0.f, 0.f, 0.f};
  for (int s = r0; s < r1; s++) {
    float4 v = ((const float4*)(sub + (size_t)s * 512))[t];
    a.x += v.x; a.y += v.y; a.z += v.z; a.w += v.w;
  }
  int c = r1 - r0;
  float inv = 1.0f / (float)(c > 0 ? c : 1);
  float4 sc4; sc4.x = a.x * inv; sc4.y = a.y * inv; sc4.z = a.z * inv; sc4.w = a.w * inv;
  *(float4*)(gsh + t * 4) = sc4;
  __syncthreads();

  float acc = P[O_L1B + t];
  const float4* wr = (const float4*)(P + O_L1W + t * 512);
  for (int kb = 0; kb < 128; kb++) {
    float4 w = wr[kb];
    int k = kb * 4;
    acc += gsh[k] * w.x + gsh[k + 1] * w.y + gsh[k + 2] * w.z + gsh[k + 3] * w.w;
  }
  hsh[t] = fmaxf(acc, 0.f);
  __syncthreads();
  if (t < 10) {
    float aa = P[O_L2B + t];
    const float* w2r = P + O_L2W + t * 128;
    for (int k = 0; k < 128; k++) aa += hsh[k] * w2r[k];
    lsh[t] = aa;
  }
  __syncthreads();
  if (t == 0) {
    float m = -1e30f;
    for (int cc = 0; cc < 10; cc++) m = fmaxf(m, lsh[cc]);
    float se = 0.f;
    for (int cc = 0; cc < 10; cc++) se += expf(lsh[cc] - m);
    lsh[10] = m + logf(se);
  }
  __syncthreads();
  if (t < 10) {
    float v = lsh[t] - lsh[10];
    if (flag) ((float*)out)[g * 10 + t] = v;
    else      ((u16*)out)[g * 10 + t] = f2bf(v);
  }
}

extern "C" void kernel_launch(void* const* d_in, const int* in_sizes, int n_in,
                              void* d_out, int out_size, void* d_ws, size_t ws_size,
                              hipStream_t stream) {
  const void* x   = d_in[0];
  const int* ei   = (const int*)d_in[1];
  const int* n2s  = (const int*)d_in[2];
  const int* s2g  = (const int*)d_in[3];

  char* ws = (char*)d_ws;
  size_t o = 0;
  auto alloc = [&](size_t b) -> void* {
    void* p = ws + o;
    o += (b + 255) & ~(size_t)255;
    return p;
  };
  int* off    = (int*)alloc((NN + 1) * 4);
  int* cnt    = (int*)alloc(NN * 4);      // cnt, cur, stats contiguous -> one memset
  int* cur    = (int*)alloc(NN * 4);
  float* stats = (float*)alloc(8 * 256 * 4);
  int* bsum   = (int*)alloc(NSCAN * 4);
  int* csr    = (int*)alloc((size_t)EE * 4);
  u16* zb0    = (u16*)alloc((size_t)NN * 128 * 2);
  u16* zb1    = (u16*)alloc((size_t)NN * 128 * 2);
  u16* H1     = (u16*)alloc((size_t)NN * 128 * 2);
  u16* H2     = (u16*)alloc((size_t)NN * 128 * 2);
  float* sub  = (float*)alloc((size_t)SS * 512 * 4);
  float* P    = (float*)alloc((size_t)NPAR * 4);
  u16* W1b    = (u16*)alloc(65536 * 2);
  u16* W2b    = (u16*)alloc(65536 * 2);

  const int* esrc = ei;
  const int* edst = ei + EE;

  size_t zspan = (char*)(stats + 8 * 256) - (char*)cnt;
  hipMemsetAsync(cnt, 0, zspan, stream);

  k_setup<<<dim3(6250), dim3(256), 0, stream>>>(
      x, edst,
      d_in[4], d_in[5], d_in[6], d_in[7], d_in[8], d_in[9], d_in[10], d_in[11],
      d_in[12], d_in[13], d_in[14], d_in[15], d_in[16],
      P, W1b, W2b, zb0, cnt);

  k_scan1<<<dim3(NSCAN), dim3(256), 0, stream>>>(cnt, bsum);
  k_scan3x<<<dim3(NSCAN), dim3(256), 0, stream>>>(cnt, bsum, off);
  k_fill<<<dim3((EE + 255) / 256), dim3(256), 0, stream>>>(esrc, edst, off, cur, csr);

  for (int l = 0; l < 4; l++) {
    const u16* Zin = (l == 0) ? zb0 : ((l & 1) ? zb1 : zb0);
    u16* Zout = (l & 1) ? zb0 : zb1;
    float* st1 = stats + (2 * l) * 256;
    float* st2 = stats + (2 * l + 1) * 256;
    k_agg_gemm<<<dim3((NN + 63) / 64), dim3(256), 0, stream>>>(
        Zin, off, csr, W1b + l * 16384, P + O_B1 + l * 128, P, l, H1, st1);
    k_bn_gemm<<<dim3((NN + 63) / 64), dim3(256), 0, stream>>>(
        H1, W2b + l * 16384, P + O_B2 + l * 128, st1, P + O_G1 + l * 128, P + O_BE1 + l * 128, H2, st2);
    k_bn_sub<<<dim3((SS + 3) / 4), dim3(256), 0, stream>>>(
        H2, st2, P + O_G2 + l * 128, P + O_BE2 + l * 128, n2s, Zout, sub, l);
  }
  k_poolhead<<<dim3(GG), dim3(128), 0, stream>>>(sub, s2g, P, x, (void*)d_out);
}